// Round 5
// baseline (891.795 us; speedup 1.0000x reference)
//
#include <hip/hip_runtime.h>
#include <cstdint>
#include <cstddef>

// ---------------------------------------------------------------------------
// Problem constants
// ---------------------------------------------------------------------------
constexpr int N_CLASSES  = 10;
constexpr int N_INTERNAL = 256;
constexpr int N_VALS     = 2 * N_CLASSES + N_INTERNAL;  // 276
constexpr int B_SZ  = 8192;
constexpr int D_IN  = 784;
constexpr int KP1   = 896;    // D_IN padded to multiple of 128 (8-phase needs K%128==0)
constexpr int H_DIM = 4096;

// ---------------------------------------------------------------------------
// Compile-time reconstruction of np.random.RandomState(0) circuit generation.
// (verified bit-exact in round 2: absmax == 0.0)
// ---------------------------------------------------------------------------
struct MTState {
  uint32_t key[624];
  int pos;
};

constexpr uint32_t mt_next(MTState& st) {
  if (st.pos == 624) {
    for (int i = 0; i < 624; ++i) {
      uint32_t y = (st.key[i] & 0x80000000u) | (st.key[(i + 1) % 624] & 0x7fffffffu);
      st.key[i] = st.key[(i + 397) % 624] ^ (y >> 1) ^ ((y & 1u) ? 0x9908b0dfu : 0u);
    }
    st.pos = 0;
  }
  uint32_t y = st.key[st.pos++];
  y ^= y >> 11;
  y ^= (y << 7) & 0x9d2c5680u;
  y ^= (y << 15) & 0xefc60000u;
  y ^= y >> 18;
  return y;
}

constexpr uint32_t interval_draw(MTState& st, uint32_t maxv) {
  if (maxv == 0u) return 0u;
  uint32_t mask = maxv;
  mask |= mask >> 1; mask |= mask >> 2; mask |= mask >> 4;
  mask |= mask >> 8; mask |= mask >> 16;
  uint32_t v = mt_next(st) & mask;
  while (v > maxv) v = mt_next(st) & mask;
  return v;
}

struct Circuit {
  int16_t prime[N_INTERNAL][3];
  int16_t sub[N_INTERNAL][3];
};

constexpr Circuit make_circuit() {
  MTState st{};
  uint32_t s = 0u;
  for (int i = 0; i < 624; ++i) {
    st.key[i] = s;
    s = 1812433253u * (s ^ (s >> 30)) + (uint32_t)i + 1u;
  }
  st.pos = 624;

  Circuit c{};
  for (int node = 0; node < N_INTERNAL; ++node) {
    const int avail = 2 * N_CLASSES + node;
    int arr[N_CLASSES] = {0, 1, 2, 3, 4, 5, 6, 7, 8, 9};
    for (int i = N_CLASSES - 1; i >= 1; --i) {
      uint32_t j = interval_draw(st, (uint32_t)i);
      int tmp = arr[i]; arr[i] = arr[j]; arr[j] = tmp;
    }
    for (int e = 0; e < 3; ++e) c.prime[node][e] = (int16_t)arr[e];
    for (int e = 0; e < 3; ++e) c.sub[node][e] = (int16_t)interval_draw(st, (uint32_t)(avail - 1));
  }
  return c;
}

constexpr Circuit CIRC = make_circuit();

// ---------------------------------------------------------------------------
// helpers
// ---------------------------------------------------------------------------
__device__ __forceinline__ uint16_t f2bf(float f) {
  uint32_t u = __builtin_bit_cast(uint32_t, f);
  uint32_t r = (u + 0x7fffu + ((u >> 16) & 1u)) >> 16;  // RNE
  return (uint16_t)r;
}
__device__ __forceinline__ float bf2f(uint16_t h) {
  uint32_t u = ((uint32_t)h) << 16;
  return __builtin_bit_cast(float, u);
}

__device__ __forceinline__ void load_lds16(const void* g, void* l) {
  __builtin_amdgcn_global_load_lds(
      (const __attribute__((address_space(1))) unsigned int*)g,
      (__attribute__((address_space(3))) unsigned int*)l, 16, 0, 0);
}

using bf16x8 = __attribute__((ext_vector_type(8))) short;
using f32x4  = __attribute__((ext_vector_type(4))) float;

__device__ __forceinline__ void dsr(bf16x8& d, uint32_t a) {
  asm volatile("ds_read_b128 %0, %1" : "=v"(d) : "v"(a));
}

// ---------------------------------------------------------------------------
// Circuit evaluation: fully unrolled, static indices only
// ---------------------------------------------------------------------------
template <int I>
__device__ __forceinline__ void eval_node(float (&vals)[N_VALS]) {
  if constexpr (I < N_INTERNAL) {
    constexpr int p0 = CIRC.prime[I][0], s0 = CIRC.sub[I][0];
    constexpr int p1 = CIRC.prime[I][1], s1 = CIRC.sub[I][1];
    constexpr int p2 = CIRC.prime[I][2], s2 = CIRC.sub[I][2];
    vals[2 * N_CLASSES + I] =
        vals[p0] * vals[s0] + vals[p1] * vals[s1] + vals[p2] * vals[s2];
    eval_node<I + 1>(vals);
  }
}

__global__ __launch_bounds__(256) void circuit_kernel(
    const float* __restrict__ probs, float* __restrict__ out, int B) {
  int r = blockIdx.x * blockDim.x + threadIdx.x;
  if (r >= B) return;
  float vals[N_VALS];
#pragma unroll
  for (int c = 0; c < N_CLASSES; ++c) {
    float p = probs[r * N_CLASSES + c];
    vals[c] = p;
    vals[N_CLASSES + c] = 1.0f - p;
  }
  eval_node<0>(vals);
  out[r] = vals[N_VALS - 1];
}

// ---------------------------------------------------------------------------
// x [B,784] f32 -> xb [B,896] bf16 (zero-padded)
// ---------------------------------------------------------------------------
__global__ __launch_bounds__(256) void convert_pad_x(
    const float* __restrict__ x, uint16_t* __restrict__ xb) {
  int idx = blockIdx.x * 256 + threadIdx.x;
  if (idx >= B_SZ * KP1) return;
  int r = idx / KP1, c = idx - r * KP1;
  xb[idx] = (c < D_IN) ? f2bf(x[(size_t)r * D_IN + c]) : (uint16_t)0;
}

// ---------------------------------------------------------------------------
// W [K,N] f32 -> Wt [N,Kp] bf16 (transpose + convert, zero-pad k in [K,Kp))
// ---------------------------------------------------------------------------
__global__ __launch_bounds__(256) void transpose_convert(
    const float* __restrict__ W, uint16_t* __restrict__ Wt,
    int K, int N, int Kp) {
  __shared__ float tile[32][33];
  const int kt = blockIdx.y * 32;
  const int nt = blockIdx.x * 32;
  const int tc = threadIdx.x & 31;
  const int tr = threadIdx.x >> 5;  // 0..7
#pragma unroll
  for (int i = 0; i < 4; ++i) {
    int k = kt + tr + i * 8;
    tile[tr + i * 8][tc] = (k < K) ? W[(size_t)k * N + nt + tc] : 0.0f;
  }
  __syncthreads();
#pragma unroll
  for (int i = 0; i < 4; ++i) {
    int n = nt + tr + i * 8;
    int k = kt + tc;
    if (k < Kp) Wt[(size_t)n * Kp + k] = f2bf(tile[tc][tr + i * 8]);
  }
}

// ---------------------------------------------------------------------------
// 256x256 8-phase bf16 MFMA GEMM (m201-style template):
//   C[M,N] = relu(A[M,K] @ Bt[N,K]^T + bias[N]), bf16 in/out, f32 accum.
// 512 threads = 8 waves (2Mx4N), per-wave 128x64 output. BK=64, 2 K-tiles/iter,
// 8 phases/iter. Quadrant order (00),(01),(11),(10) with A reused 2 phases and
// both B quadrants register-resident: ds_read_b128/phase = 12/4/8/0 (48/iter,
// was 80 — R4 showed the 80-read variant is LDS-BW-bound at MfmaUtil 36%).
// LDS 128 KiB: A[2][256][64]+B[2][256][64] bf16, row-permuted halves +
// slot^=(row&7) XOR swizzle; staging = linear LDS dest + inverse-swizzled src.
// Counted vmcnt(6) at phases 4/8 only; raw s_barrier; setprio around MFMA.
// Requires: M%256==0, N%256==0, K%128==0, K>=256.
// ---------------------------------------------------------------------------
template <int MH, int NH, bool RA, bool RB, int VM, typename F>
__device__ __forceinline__ void phase_t(
    uint32_t aB, uint32_t bB, uint32_t s0v, uint32_t s1v,
    bf16x8 (&Ar)[4][2], bf16x8 (&Br)[2][2][2], f32x4 (&acc)[2][2][4][2],
    F&& stage) {
  // 1. ds_read fragments (volatile asm — pinned within the phase's barriers)
  if constexpr (RA) {
#pragma unroll
    for (int m = 0; m < 4; ++m) {
      dsr(Ar[m][0], aB + MH * 16384 + m * 2048 + s0v);
      dsr(Ar[m][1], aB + MH * 16384 + m * 2048 + s1v);
    }
  }
  if constexpr (RB) {
#pragma unroll
    for (int nf = 0; nf < 2; ++nf) {
      dsr(Br[NH][nf][0], bB + NH * 16384 + nf * 2048 + s0v);
      dsr(Br[NH][nf][1], bB + NH * 16384 + nf * 2048 + s1v);
    }
  }
  // 2. stage issues (global_load_lds) for this phase
  stage();
  if constexpr (RA && RB) asm volatile("s_waitcnt lgkmcnt(8)" ::: "memory");
  // 3. barrier; wait LDS reads; MFMA cluster
  __builtin_amdgcn_s_barrier();
  asm volatile("s_waitcnt lgkmcnt(0)" ::: "memory");
  __builtin_amdgcn_sched_barrier(0);  // rule #18: pin MFMAs below the wait
  __builtin_amdgcn_s_setprio(1);
#pragma unroll
  for (int m = 0; m < 4; ++m)
#pragma unroll
    for (int nf = 0; nf < 2; ++nf) {
      acc[MH][NH][m][nf] = __builtin_amdgcn_mfma_f32_16x16x32_bf16(
          Ar[m][0], Br[NH][nf][0], acc[MH][NH][m][nf], 0, 0, 0);
      acc[MH][NH][m][nf] = __builtin_amdgcn_mfma_f32_16x16x32_bf16(
          Ar[m][1], Br[NH][nf][1], acc[MH][NH][m][nf], 0, 0, 0);
    }
  __builtin_amdgcn_s_setprio(0);
  // 4. counted vmcnt (confirms the tile read after the NEXT barrier)
  if constexpr (VM >= 0) asm volatile("s_waitcnt vmcnt(%0)" :: "i"(VM) : "memory");
  __builtin_amdgcn_s_barrier();
}

__global__ __launch_bounds__(512, 2) void gemm256_bf16(
    const uint16_t* __restrict__ A, const uint16_t* __restrict__ Bt,
    const float* __restrict__ bias, uint16_t* __restrict__ C,
    int M, int N, int K) {
  extern __shared__ char smem[];

  const int t    = threadIdx.x;
  const int t16  = t * 16;
  const int lane = t & 63;
  const int wid  = t >> 6;
  const int wr   = wid >> 2;   // 0..1
  const int wc   = wid & 3;    // 0..3
  const int fr   = lane & 15;
  const int fq   = lane >> 4;

  // XCD-aware bijective swizzle (nwg % 8 == 0 for both layers)
  const int gx = gridDim.x, gy = gridDim.y;
  const int nwg = gx * gy;
  const int id  = blockIdx.y * gx + blockIdx.x;
  const int cpx = nwg >> 3;
  const int sid = (id & 7) * cpx + (id >> 3);
  const int row0 = (sid / gx) * 256;
  const int col0 = (sid % gx) * 256;

  const size_t Kb = (size_t)K * 2;
  const char* Ab = (const char*)A;
  const char* Bb = (const char*)Bt;

  // ---- per-thread staging source offsets (inverse swizzle + row permutation)
  size_t srcA00, srcA01, srcA10, srcA11, srcB00, srcB01, srcB10, srcB11;
#define MKSRC(h, j, SA_, SB_) { \
    const int off_ = (j) * 8192 + t16; \
    const int p_ = (h) * 128 + (off_ >> 7); \
    const int s_ = (off_ >> 4) & 7, sg_ = s_ ^ (p_ & 7); \
    const int ga_ = (((p_ >> 6) & 1) * 128) + (h) * 64 + (p_ & 63); \
    const int gb_ = (((p_ >> 5) & 3) * 64) + (h) * 32 + (p_ & 31); \
    SA_ = (size_t)(row0 + ga_) * Kb + sg_ * 16; \
    SB_ = (size_t)(col0 + gb_) * Kb + sg_ * 16; }
  MKSRC(0, 0, srcA00, srcB00)
  MKSRC(0, 1, srcA01, srcB01)
  MKSRC(1, 0, srcA10, srcB10)
  MKSRC(1, 1, srcA11, srcB11)
#undef MKSRC

#define STAGE_A(v, h, kt) do { const char* g_ = Ab + (size_t)(kt) * 128; \
    load_lds16(g_ + srcA##h##0, smem + (v) * 32768 + (h) * 16384 + t16); \
    load_lds16(g_ + srcA##h##1, smem + (v) * 32768 + (h) * 16384 + 8192 + t16); } while (0)
#define STAGE_B(v, h, kt) do { const char* g_ = Bb + (size_t)(kt) * 128; \
    load_lds16(g_ + srcB##h##0, smem + 65536 + (v) * 32768 + (h) * 16384 + t16); \
    load_lds16(g_ + srcB##h##1, smem + 65536 + (v) * 32768 + (h) * 16384 + 8192 + t16); } while (0)

  // ---- per-thread ds_read bases (swizzled)
  const uint32_t smb = (uint32_t)(size_t)(__attribute__((address_space(3))) char*)smem;
  const uint32_t aB0 = smb + (uint32_t)((wr * 64 + fr) * 128);
  const uint32_t bB0 = smb + 65536u + (uint32_t)((wc * 32 + fr) * 128);
  const uint32_t s0v = (uint32_t)(((0 * 4 + fq) ^ (fr & 7)) * 16);
  const uint32_t s1v = (uint32_t)(((1 * 4 + fq) ^ (fr & 7)) * 16);

  f32x4 acc[2][2][4][2];
#pragma unroll
  for (int a = 0; a < 2; ++a)
#pragma unroll
    for (int b = 0; b < 2; ++b)
#pragma unroll
      for (int m = 0; m < 4; ++m)
#pragma unroll
        for (int n = 0; n < 2; ++n) {
          acc[a][b][m][n][0] = 0.f; acc[a][b][m][n][1] = 0.f;
          acc[a][b][m][n][2] = 0.f; acc[a][b][m][n][3] = 0.f;
        }

  bf16x8 Ar[4][2], Br[2][2][2];

  // ---- prologue: tile0 fully, tile1 minus A1; confirm tile0; barrier
  STAGE_B(0, 0, 0); STAGE_A(0, 0, 0); STAGE_B(0, 1, 0); STAGE_A(0, 1, 0);
  STAGE_B(1, 0, 1); STAGE_A(1, 0, 1); STAGE_B(1, 1, 1);
  asm volatile("s_waitcnt vmcnt(6)" ::: "memory");
  __builtin_amdgcn_s_barrier();

#define PH(MH_, NH_, RA_, RB_, VM_, BUF_, ...) \
  phase_t<MH_, NH_, RA_, RB_, VM_>(aB0 + (BUF_) * 32768, bB0 + (BUF_) * 32768, \
                                   s0v, s1v, Ar, Br, acc, [&]() { __VA_ARGS__ })

  const int NI = K >> 7;  // iterations; 2 K-tiles each
  int i = 0;
  for (; i < NI - 1; ++i) {
    const int ktb = 2 * i + 1, ktc = 2 * i + 2, ktd = 2 * i + 3;
    PH(0, 0, true,  true,  -1, 0, STAGE_A(1, 1, ktb); );
    PH(0, 1, false, true,  -1, 0, STAGE_B(0, 0, ktc); );
    PH(1, 1, true,  false, -1, 0, );
    PH(1, 0, false, false,  6, 0, STAGE_A(0, 0, ktc); STAGE_B(0, 1, ktc); );
    PH(0, 0, true,  true,  -1, 1, STAGE_A(0, 1, ktc); );
    PH(0, 1, false, true,  -1, 1, STAGE_B(1, 0, ktd); );
    PH(1, 1, true,  false, -1, 1, );
    PH(1, 0, false, false,  6, 1, STAGE_A(1, 0, ktd); STAGE_B(1, 1, ktd); );
  }
  // peeled last iteration: finish staging tile b, drain, no further stages
  {
    const int ktb = 2 * i + 1;
    PH(0, 0, true,  true,  -1, 0, STAGE_A(1, 1, ktb); );
    PH(0, 1, false, true,  -1, 0, );
    PH(1, 1, true,  false, -1, 0, );
    PH(1, 0, false, false,  0, 0, );
    PH(0, 0, true,  true,  -1, 1, );
    PH(0, 1, false, true,  -1, 1, );
    PH(1, 1, true,  false, -1, 1, );
    PH(1, 0, false, false, -1, 1, );
  }
#undef PH
#undef STAGE_A
#undef STAGE_B

  // ---- epilogue: bias + relu + bf16 store
  // C/D layout: col = lane&15, row = (lane>>4)*4 + j   [measured m89]
#pragma unroll
  for (int mh = 0; mh < 2; ++mh)
#pragma unroll
    for (int nh = 0; nh < 2; ++nh)
#pragma unroll
      for (int m = 0; m < 4; ++m)
#pragma unroll
        for (int nf = 0; nf < 2; ++nf) {
          const int row = row0 + wr * 128 + mh * 64 + m * 16 + fq * 4;
          const int col = col0 + wc * 64 + nh * 32 + nf * 16 + fr;
          const float bv = bias[col];
          const size_t base = (size_t)row * N + col;
#pragma unroll
          for (int j = 0; j < 4; ++j) {
            float v = acc[mh][nh][m][nf][j] + bv;
            v = fmaxf(v, 0.0f);
            C[base + (size_t)j * N] = f2bf(v);
          }
        }
}

// ---------------------------------------------------------------------------
// logits (K=4096, N=10) + softmax -> probs[B,10]; one wave per row; h2 bf16
// ---------------------------------------------------------------------------
__global__ __launch_bounds__(256) void logits_softmax_kernel(
    const uint16_t* __restrict__ h2, const float* __restrict__ W3,
    const float* __restrict__ b3, float* __restrict__ probs, int B) {
  const int wave = threadIdx.x >> 6;
  const int lane = threadIdx.x & 63;
  const int row  = blockIdx.x * 4 + wave;
  if (row >= B) return;

  const uint16_t* hrow = h2 + (size_t)row * H_DIM;
  float acc[N_CLASSES];
#pragma unroll
  for (int c = 0; c < N_CLASSES; ++c) acc[c] = 0.0f;

#pragma unroll
  for (int it = 0; it < H_DIM / (64 * 8); ++it) {
    const int k0 = (it * 64 + lane) * 8;
    ushort4 u0 = *reinterpret_cast<const ushort4*>(hrow + k0);
    ushort4 u1 = *reinterpret_cast<const ushort4*>(hrow + k0 + 4);
    float hv[8] = {bf2f(u0.x), bf2f(u0.y), bf2f(u0.z), bf2f(u0.w),
                   bf2f(u1.x), bf2f(u1.y), bf2f(u1.z), bf2f(u1.w)};
#pragma unroll
    for (int q = 0; q < 8; ++q) {
      const float* wrow = W3 + (size_t)(k0 + q) * N_CLASSES;
#pragma unroll
      for (int c = 0; c < N_CLASSES; ++c) acc[c] = fmaf(hv[q], wrow[c], acc[c]);
    }
  }

#pragma unroll
  for (int c = 0; c < N_CLASSES; ++c) {
#pragma unroll
    for (int s = 32; s >= 1; s >>= 1) acc[c] += __shfl_xor(acc[c], s, 64);
  }

  if (lane == 0) {
    float l[N_CLASSES], m = -3.0e38f;
#pragma unroll
    for (int c = 0; c < N_CLASSES; ++c) {
      l[c] = acc[c] + b3[c];
      m = fmaxf(m, l[c]);
    }
    float sum = 0.0f;
#pragma unroll
    for (int c = 0; c < N_CLASSES; ++c) {
      l[c] = expf(l[c] - m);
      sum += l[c];
    }
    const float inv = 1.0f / sum;
#pragma unroll
    for (int c = 0; c < N_CLASSES; ++c) probs[row * N_CLASSES + c] = l[c] * inv;
  }
}

// ---------------------------------------------------------------------------
// launch.  ws layout (bf16 unless noted), total ~182 MB:
//   xb[8192*896] w1t[4096*896] w2t[4096*4096] h1[8192*4096] h2[8192*4096]
//   probs f32[8192*10]
// ---------------------------------------------------------------------------
extern "C" void kernel_launch(void* const* d_in, const int* in_sizes, int n_in,
                              void* d_out, int out_size, void* d_ws, size_t ws_size,
                              hipStream_t stream) {
  const float* x  = (const float*)d_in[0];
  const float* W1 = (const float*)d_in[1];
  const float* b1 = (const float*)d_in[2];
  const float* W2 = (const float*)d_in[3];
  const float* b2 = (const float*)d_in[4];
  const float* W3 = (const float*)d_in[5];
  const float* b3 = (const float*)d_in[6];
  float* out = (float*)d_out;

  uint16_t* xb  = (uint16_t*)d_ws;
  uint16_t* w1t = xb  + (size_t)B_SZ * KP1;
  uint16_t* w2t = w1t + (size_t)H_DIM * KP1;
  uint16_t* h1  = w2t + (size_t)H_DIM * H_DIM;
  uint16_t* h2  = h1  + (size_t)B_SZ * H_DIM;
  float* probs  = (float*)(h2 + (size_t)B_SZ * H_DIM);

  // allow 128 KiB dynamic LDS for the 8-phase GEMM (host-side attr, capture-safe)
  (void)hipFuncSetAttribute((const void*)gemm256_bf16,
                            hipFuncAttributeMaxDynamicSharedMemorySize, 131072);

  dim3 blk(256);

  // input conversions
  convert_pad_x<<<dim3((B_SZ * KP1 + 255) / 256), blk, 0, stream>>>(x, xb);
  transpose_convert<<<dim3(H_DIM / 32, KP1 / 32), blk, 0, stream>>>(W1, w1t, D_IN, H_DIM, KP1);
  transpose_convert<<<dim3(H_DIM / 32, H_DIM / 32), blk, 0, stream>>>(W2, w2t, H_DIM, H_DIM, H_DIM);

  // layer 1: h1 = relu(xb @ w1t^T + b1)   [8192,896]x[896,4096]
  gemm256_bf16<<<dim3(H_DIM / 256, B_SZ / 256), dim3(512), 131072, stream>>>(
      xb, w1t, b1, h1, B_SZ, H_DIM, KP1);

  // layer 2: h2 = relu(h1 @ w2t^T + b2)   [8192,4096]x[4096,4096]
  gemm256_bf16<<<dim3(H_DIM / 256, B_SZ / 256), dim3(512), 131072, stream>>>(
      h1, w2t, b2, h2, B_SZ, H_DIM, H_DIM);

  // layer 3 + softmax -> probs
  logits_softmax_kernel<<<dim3(B_SZ / 4), blk, 0, stream>>>(h2, W3, b3, probs, B_SZ);

  // circuit eval -> out[B]
  circuit_kernel<<<dim3(B_SZ / 256), blk, 0, stream>>>(probs, out, B_SZ);
}

// Round 6
// 890.236 us; speedup vs baseline: 1.0018x; 1.0018x over previous
//
#include <hip/hip_runtime.h>
#include <cstdint>
#include <cstddef>

// ---------------------------------------------------------------------------
// Problem constants
// ---------------------------------------------------------------------------
constexpr int N_CLASSES  = 10;
constexpr int N_INTERNAL = 256;
constexpr int N_VALS     = 2 * N_CLASSES + N_INTERNAL;  // 276
constexpr int B_SZ  = 8192;
constexpr int D_IN  = 784;
constexpr int KP1   = 896;    // D_IN padded to multiple of 128 (8-phase needs K%128==0)
constexpr int H_DIM = 4096;

// ---------------------------------------------------------------------------
// Compile-time reconstruction of np.random.RandomState(0) circuit generation.
// (verified bit-exact in round 2: absmax == 0.0)
// ---------------------------------------------------------------------------
struct MTState {
  uint32_t key[624];
  int pos;
};

constexpr uint32_t mt_next(MTState& st) {
  if (st.pos == 624) {
    for (int i = 0; i < 624; ++i) {
      uint32_t y = (st.key[i] & 0x80000000u) | (st.key[(i + 1) % 624] & 0x7fffffffu);
      st.key[i] = st.key[(i + 397) % 624] ^ (y >> 1) ^ ((y & 1u) ? 0x9908b0dfu : 0u);
    }
    st.pos = 0;
  }
  uint32_t y = st.key[st.pos++];
  y ^= y >> 11;
  y ^= (y << 7) & 0x9d2c5680u;
  y ^= (y << 15) & 0xefc60000u;
  y ^= y >> 18;
  return y;
}

constexpr uint32_t interval_draw(MTState& st, uint32_t maxv) {
  if (maxv == 0u) return 0u;
  uint32_t mask = maxv;
  mask |= mask >> 1; mask |= mask >> 2; mask |= mask >> 4;
  mask |= mask >> 8; mask |= mask >> 16;
  uint32_t v = mt_next(st) & mask;
  while (v > maxv) v = mt_next(st) & mask;
  return v;
}

struct Circuit {
  int16_t prime[N_INTERNAL][3];
  int16_t sub[N_INTERNAL][3];
};

constexpr Circuit make_circuit() {
  MTState st{};
  uint32_t s = 0u;
  for (int i = 0; i < 624; ++i) {
    st.key[i] = s;
    s = 1812433253u * (s ^ (s >> 30)) + (uint32_t)i + 1u;
  }
  st.pos = 624;

  Circuit c{};
  for (int node = 0; node < N_INTERNAL; ++node) {
    const int avail = 2 * N_CLASSES + node;
    int arr[N_CLASSES] = {0, 1, 2, 3, 4, 5, 6, 7, 8, 9};
    for (int i = N_CLASSES - 1; i >= 1; --i) {
      uint32_t j = interval_draw(st, (uint32_t)i);
      int tmp = arr[i]; arr[i] = arr[j]; arr[j] = tmp;
    }
    for (int e = 0; e < 3; ++e) c.prime[node][e] = (int16_t)arr[e];
    for (int e = 0; e < 3; ++e) c.sub[node][e] = (int16_t)interval_draw(st, (uint32_t)(avail - 1));
  }
  return c;
}

constexpr Circuit CIRC = make_circuit();

// ---------------------------------------------------------------------------
// helpers
// ---------------------------------------------------------------------------
__device__ __forceinline__ uint16_t f2bf(float f) {
  uint32_t u = __builtin_bit_cast(uint32_t, f);
  uint32_t r = (u + 0x7fffu + ((u >> 16) & 1u)) >> 16;  // RNE
  return (uint16_t)r;
}
__device__ __forceinline__ float bf2f(uint16_t h) {
  uint32_t u = ((uint32_t)h) << 16;
  return __builtin_bit_cast(float, u);
}

__device__ __forceinline__ void load_lds16(const void* g, void* l) {
  __builtin_amdgcn_global_load_lds(
      (const __attribute__((address_space(1))) unsigned int*)g,
      (__attribute__((address_space(3))) unsigned int*)l, 16, 0, 0);
}

using bf16x8 = __attribute__((ext_vector_type(8))) short;
using f32x4  = __attribute__((ext_vector_type(4))) float;

__device__ __forceinline__ void dsr(bf16x8& d, uint32_t a) {
  asm volatile("ds_read_b128 %0, %1" : "=v"(d) : "v"(a));
}

// ---------------------------------------------------------------------------
// Circuit evaluation: fully unrolled, static indices only
// ---------------------------------------------------------------------------
template <int I>
__device__ __forceinline__ void eval_node(float (&vals)[N_VALS]) {
  if constexpr (I < N_INTERNAL) {
    constexpr int p0 = CIRC.prime[I][0], s0 = CIRC.sub[I][0];
    constexpr int p1 = CIRC.prime[I][1], s1 = CIRC.sub[I][1];
    constexpr int p2 = CIRC.prime[I][2], s2 = CIRC.sub[I][2];
    vals[2 * N_CLASSES + I] =
        vals[p0] * vals[s0] + vals[p1] * vals[s1] + vals[p2] * vals[s2];
    eval_node<I + 1>(vals);
  }
}

__global__ __launch_bounds__(256) void circuit_kernel(
    const float* __restrict__ probs, float* __restrict__ out, int B) {
  int r = blockIdx.x * blockDim.x + threadIdx.x;
  if (r >= B) return;
  float vals[N_VALS];
#pragma unroll
  for (int c = 0; c < N_CLASSES; ++c) {
    float p = probs[r * N_CLASSES + c];
    vals[c] = p;
    vals[N_CLASSES + c] = 1.0f - p;
  }
  eval_node<0>(vals);
  out[r] = vals[N_VALS - 1];
}

// ---------------------------------------------------------------------------
// x [B,784] f32 -> xb [B,896] bf16 (zero-padded)
// ---------------------------------------------------------------------------
__global__ __launch_bounds__(256) void convert_pad_x(
    const float* __restrict__ x, uint16_t* __restrict__ xb) {
  int idx = blockIdx.x * 256 + threadIdx.x;
  if (idx >= B_SZ * KP1) return;
  int r = idx / KP1, c = idx - r * KP1;
  xb[idx] = (c < D_IN) ? f2bf(x[(size_t)r * D_IN + c]) : (uint16_t)0;
}

// ---------------------------------------------------------------------------
// W [K,N] f32 -> Wt [N,Kp] bf16 (transpose + convert, zero-pad k in [K,Kp))
// ---------------------------------------------------------------------------
__global__ __launch_bounds__(256) void transpose_convert(
    const float* __restrict__ W, uint16_t* __restrict__ Wt,
    int K, int N, int Kp) {
  __shared__ float tile[32][33];
  const int kt = blockIdx.y * 32;
  const int nt = blockIdx.x * 32;
  const int tc = threadIdx.x & 31;
  const int tr = threadIdx.x >> 5;  // 0..7
#pragma unroll
  for (int i = 0; i < 4; ++i) {
    int k = kt + tr + i * 8;
    tile[tr + i * 8][tc] = (k < K) ? W[(size_t)k * N + nt + tc] : 0.0f;
  }
  __syncthreads();
#pragma unroll
  for (int i = 0; i < 4; ++i) {
    int n = nt + tr + i * 8;
    int k = kt + tc;
    if (k < Kp) Wt[(size_t)n * Kp + k] = f2bf(tile[tc][tr + i * 8]);
  }
}

// ---------------------------------------------------------------------------
// 256x256 8-phase bf16 MFMA GEMM (m201-style template):
//   C[M,N] = relu(A[M,K] @ Bt[N,K]^T + bias[N]), bf16 in/out, f32 accum.
// 512 threads = 8 waves (2Mx4N), per-wave 128x64 output. BK=64, 2 K-tiles/iter,
// 8 phases/iter. Quadrant order (00),(01),(11),(10), A reused 2 phases, both B
// quadrants register-resident: ds_read_b128/phase = 12/4/8/0 (48/iter).
// __launch_bounds__(512,1): R5 showed (512,2) pins VGPR=128 and SPILLS the
// +16-reg Br residency to scratch (FETCH x2, dur x2). Occupancy is LDS-bound
// at 1 block/CU (128 KiB) regardless, so the higher VGPR cap costs nothing.
// LDS 128 KiB: A[2][256][64]+B[2][256][64] bf16, row-permuted halves +
// slot^=(row&7) XOR swizzle; staging = linear LDS dest + inverse-swizzled src.
// Counted vmcnt(6) at phases 4/8 only; raw s_barrier; setprio around MFMA.
// Requires: M%256==0, N%256==0, K%128==0, K>=256.
// ---------------------------------------------------------------------------
template <int MH, int NH, bool RA, bool RB, int VM, typename F>
__device__ __forceinline__ void phase_t(
    uint32_t aB, uint32_t bB, uint32_t s0v, uint32_t s1v,
    bf16x8 (&Ar)[4][2], bf16x8 (&Br)[2][2][2], f32x4 (&acc)[2][2][4][2],
    F&& stage) {
  // 1. ds_read fragments (volatile asm — pinned within the phase's barriers)
  if constexpr (RA) {
#pragma unroll
    for (int m = 0; m < 4; ++m) {
      dsr(Ar[m][0], aB + MH * 16384 + m * 2048 + s0v);
      dsr(Ar[m][1], aB + MH * 16384 + m * 2048 + s1v);
    }
  }
  if constexpr (RB) {
#pragma unroll
    for (int nf = 0; nf < 2; ++nf) {
      dsr(Br[NH][nf][0], bB + NH * 16384 + nf * 2048 + s0v);
      dsr(Br[NH][nf][1], bB + NH * 16384 + nf * 2048 + s1v);
    }
  }
  // 2. stage issues (global_load_lds) for this phase
  stage();
  // 3. barrier; wait LDS reads; MFMA cluster
  __builtin_amdgcn_s_barrier();
  asm volatile("s_waitcnt lgkmcnt(0)" ::: "memory");
  __builtin_amdgcn_sched_barrier(0);  // rule #18: pin MFMAs below the wait
  __builtin_amdgcn_s_setprio(1);
#pragma unroll
  for (int m = 0; m < 4; ++m)
#pragma unroll
    for (int nf = 0; nf < 2; ++nf) {
      acc[MH][NH][m][nf] = __builtin_amdgcn_mfma_f32_16x16x32_bf16(
          Ar[m][0], Br[NH][nf][0], acc[MH][NH][m][nf], 0, 0, 0);
      acc[MH][NH][m][nf] = __builtin_amdgcn_mfma_f32_16x16x32_bf16(
          Ar[m][1], Br[NH][nf][1], acc[MH][NH][m][nf], 0, 0, 0);
    }
  __builtin_amdgcn_s_setprio(0);
  // 4. counted vmcnt (confirms the tile read after the NEXT barrier)
  if constexpr (VM >= 0) asm volatile("s_waitcnt vmcnt(%0)" :: "i"(VM) : "memory");
  __builtin_amdgcn_s_barrier();
}

__global__ __launch_bounds__(512, 1) void gemm256_bf16(
    const uint16_t* __restrict__ A, const uint16_t* __restrict__ Bt,
    const float* __restrict__ bias, uint16_t* __restrict__ C,
    int M, int N, int K) {
  extern __shared__ char smem[];

  const int t    = threadIdx.x;
  const int t16  = t * 16;
  const int lane = t & 63;
  const int wid  = t >> 6;
  const int wr   = wid >> 2;   // 0..1
  const int wc   = wid & 3;    // 0..3
  const int fr   = lane & 15;
  const int fq   = lane >> 4;

  // XCD-aware bijective swizzle (nwg % 8 == 0 for both layers)
  const int gx = gridDim.x, gy = gridDim.y;
  const int nwg = gx * gy;
  const int id  = blockIdx.y * gx + blockIdx.x;
  const int cpx = nwg >> 3;
  const int sid = (id & 7) * cpx + (id >> 3);
  const int row0 = (sid / gx) * 256;
  const int col0 = (sid % gx) * 256;

  const size_t Kb = (size_t)K * 2;
  const char* Ab = (const char*)A;
  const char* Bb = (const char*)Bt;

  // ---- per-thread staging source offsets (inverse swizzle + row permutation)
  size_t srcA00, srcA01, srcA10, srcA11, srcB00, srcB01, srcB10, srcB11;
#define MKSRC(h, j, SA_, SB_) { \
    const int off_ = (j) * 8192 + t16; \
    const int p_ = (h) * 128 + (off_ >> 7); \
    const int s_ = (off_ >> 4) & 7, sg_ = s_ ^ (p_ & 7); \
    const int ga_ = (((p_ >> 6) & 1) * 128) + (h) * 64 + (p_ & 63); \
    const int gb_ = (((p_ >> 5) & 3) * 64) + (h) * 32 + (p_ & 31); \
    SA_ = (size_t)(row0 + ga_) * Kb + sg_ * 16; \
    SB_ = (size_t)(col0 + gb_) * Kb + sg_ * 16; }
  MKSRC(0, 0, srcA00, srcB00)
  MKSRC(0, 1, srcA01, srcB01)
  MKSRC(1, 0, srcA10, srcB10)
  MKSRC(1, 1, srcA11, srcB11)
#undef MKSRC

#define STAGE_A(v, h, kt) do { const char* g_ = Ab + (size_t)(kt) * 128; \
    load_lds16(g_ + srcA##h##0, smem + (v) * 32768 + (h) * 16384 + t16); \
    load_lds16(g_ + srcA##h##1, smem + (v) * 32768 + (h) * 16384 + 8192 + t16); } while (0)
#define STAGE_B(v, h, kt) do { const char* g_ = Bb + (size_t)(kt) * 128; \
    load_lds16(g_ + srcB##h##0, smem + 65536 + (v) * 32768 + (h) * 16384 + t16); \
    load_lds16(g_ + srcB##h##1, smem + 65536 + (v) * 32768 + (h) * 16384 + 8192 + t16); } while (0)

  // ---- per-thread ds_read bases (swizzled)
  const uint32_t smb = (uint32_t)(size_t)(__attribute__((address_space(3))) char*)smem;
  const uint32_t aB0 = smb + (uint32_t)((wr * 64 + fr) * 128);
  const uint32_t bB0 = smb + 65536u + (uint32_t)((wc * 32 + fr) * 128);
  const uint32_t s0v = (uint32_t)(((0 * 4 + fq) ^ (fr & 7)) * 16);
  const uint32_t s1v = (uint32_t)(((1 * 4 + fq) ^ (fr & 7)) * 16);

  f32x4 acc[2][2][4][2];
#pragma unroll
  for (int a = 0; a < 2; ++a)
#pragma unroll
    for (int b = 0; b < 2; ++b)
#pragma unroll
      for (int m = 0; m < 4; ++m)
#pragma unroll
        for (int n = 0; n < 2; ++n) {
          acc[a][b][m][n][0] = 0.f; acc[a][b][m][n][1] = 0.f;
          acc[a][b][m][n][2] = 0.f; acc[a][b][m][n][3] = 0.f;
        }

  bf16x8 Ar[4][2], Br[2][2][2];

  // ---- prologue: tile0 fully, tile1 minus A1; confirm tile0; barrier
  STAGE_B(0, 0, 0); STAGE_A(0, 0, 0); STAGE_B(0, 1, 0); STAGE_A(0, 1, 0);
  STAGE_B(1, 0, 1); STAGE_A(1, 0, 1); STAGE_B(1, 1, 1);
  asm volatile("s_waitcnt vmcnt(6)" ::: "memory");
  __builtin_amdgcn_s_barrier();

#define PH(MH_, NH_, RA_, RB_, VM_, BUF_, ...) \
  phase_t<MH_, NH_, RA_, RB_, VM_>(aB0 + (BUF_) * 32768, bB0 + (BUF_) * 32768, \
                                   s0v, s1v, Ar, Br, acc, [&]() { __VA_ARGS__ })

  const int NI = K >> 7;  // iterations; 2 K-tiles each
  int i = 0;
  for (; i < NI - 1; ++i) {
    const int ktb = 2 * i + 1, ktc = 2 * i + 2, ktd = 2 * i + 3;
    PH(0, 0, true,  true,  -1, 0, STAGE_A(1, 1, ktb); );
    PH(0, 1, false, true,  -1, 0, STAGE_B(0, 0, ktc); );
    PH(1, 1, true,  false, -1, 0, );
    PH(1, 0, false, false,  6, 0, STAGE_A(0, 0, ktc); STAGE_B(0, 1, ktc); );
    PH(0, 0, true,  true,  -1, 1, STAGE_A(0, 1, ktc); );
    PH(0, 1, false, true,  -1, 1, STAGE_B(1, 0, ktd); );
    PH(1, 1, true,  false, -1, 1, );
    PH(1, 0, false, false,  6, 1, STAGE_A(1, 0, ktd); STAGE_B(1, 1, ktd); );
  }
  // peeled last iteration: finish staging tile b, drain, no further stages
  {
    const int ktb = 2 * i + 1;
    PH(0, 0, true,  true,  -1, 0, STAGE_A(1, 1, ktb); );
    PH(0, 1, false, true,  -1, 0, );
    PH(1, 1, true,  false, -1, 0, );
    PH(1, 0, false, false,  0, 0, );
    PH(0, 0, true,  true,  -1, 1, );
    PH(0, 1, false, true,  -1, 1, );
    PH(1, 1, true,  false, -1, 1, );
    PH(1, 0, false, false, -1, 1, );
  }
#undef PH
#undef STAGE_A
#undef STAGE_B

  // ---- epilogue: bias + relu + bf16 store
  // C/D layout: col = lane&15, row = (lane>>4)*4 + j   [measured m89]
#pragma unroll
  for (int mh = 0; mh < 2; ++mh)
#pragma unroll
    for (int nh = 0; nh < 2; ++nh)
#pragma unroll
      for (int m = 0; m < 4; ++m)
#pragma unroll
        for (int nf = 0; nf < 2; ++nf) {
          const int row = row0 + wr * 128 + mh * 64 + m * 16 + fq * 4;
          const int col = col0 + wc * 64 + nh * 32 + nf * 16 + fr;
          const float bv = bias[col];
          const size_t base = (size_t)row * N + col;
#pragma unroll
          for (int j = 0; j < 4; ++j) {
            float v = acc[mh][nh][m][nf][j] + bv;
            v = fmaxf(v, 0.0f);
            C[base + (size_t)j * N] = f2bf(v);
          }
        }
}

// ---------------------------------------------------------------------------
// logits (K=4096, N=10) + softmax -> probs[B,10]; one wave per row; h2 bf16
// ---------------------------------------------------------------------------
__global__ __launch_bounds__(256) void logits_softmax_kernel(
    const uint16_t* __restrict__ h2, const float* __restrict__ W3,
    const float* __restrict__ b3, float* __restrict__ probs, int B) {
  const int wave = threadIdx.x >> 6;
  const int lane = threadIdx.x & 63;
  const int row  = blockIdx.x * 4 + wave;
  if (row >= B) return;

  const uint16_t* hrow = h2 + (size_t)row * H_DIM;
  float acc[N_CLASSES];
#pragma unroll
  for (int c = 0; c < N_CLASSES; ++c) acc[c] = 0.0f;

#pragma unroll
  for (int it = 0; it < H_DIM / (64 * 8); ++it) {
    const int k0 = (it * 64 + lane) * 8;
    ushort4 u0 = *reinterpret_cast<const ushort4*>(hrow + k0);
    ushort4 u1 = *reinterpret_cast<const ushort4*>(hrow + k0 + 4);
    float hv[8] = {bf2f(u0.x), bf2f(u0.y), bf2f(u0.z), bf2f(u0.w),
                   bf2f(u1.x), bf2f(u1.y), bf2f(u1.z), bf2f(u1.w)};
#pragma unroll
    for (int q = 0; q < 8; ++q) {
      const float* wrow = W3 + (size_t)(k0 + q) * N_CLASSES;
#pragma unroll
      for (int c = 0; c < N_CLASSES; ++c) acc[c] = fmaf(hv[q], wrow[c], acc[c]);
    }
  }

#pragma unroll
  for (int c = 0; c < N_CLASSES; ++c) {
#pragma unroll
    for (int s = 32; s >= 1; s >>= 1) acc[c] += __shfl_xor(acc[c], s, 64);
  }

  if (lane == 0) {
    float l[N_CLASSES], m = -3.0e38f;
#pragma unroll
    for (int c = 0; c < N_CLASSES; ++c) {
      l[c] = acc[c] + b3[c];
      m = fmaxf(m, l[c]);
    }
    float sum = 0.0f;
#pragma unroll
    for (int c = 0; c < N_CLASSES; ++c) {
      l[c] = expf(l[c] - m);
      sum += l[c];
    }
    const float inv = 1.0f / sum;
#pragma unroll
    for (int c = 0; c < N_CLASSES; ++c) probs[row * N_CLASSES + c] = l[c] * inv;
  }
}

// ---------------------------------------------------------------------------
// launch.  ws layout (bf16 unless noted), total ~182 MB:
//   xb[8192*896] w1t[4096*896] w2t[4096*4096] h1[8192*4096] h2[8192*4096]
//   probs f32[8192*10]
// ---------------------------------------------------------------------------
extern "C" void kernel_launch(void* const* d_in, const int* in_sizes, int n_in,
                              void* d_out, int out_size, void* d_ws, size_t ws_size,
                              hipStream_t stream) {
  const float* x  = (const float*)d_in[0];
  const float* W1 = (const float*)d_in[1];
  const float* b1 = (const float*)d_in[2];
  const float* W2 = (const float*)d_in[3];
  const float* b2 = (const float*)d_in[4];
  const float* W3 = (const float*)d_in[5];
  const float* b3 = (const float*)d_in[6];
  float* out = (float*)d_out;

  uint16_t* xb  = (uint16_t*)d_ws;
  uint16_t* w1t = xb  + (size_t)B_SZ * KP1;
  uint16_t* w2t = w1t + (size_t)H_DIM * KP1;
  uint16_t* h1  = w2t + (size_t)H_DIM * H_DIM;
  uint16_t* h2  = h1  + (size_t)B_SZ * H_DIM;
  float* probs  = (float*)(h2 + (size_t)B_SZ * H_DIM);

  // allow 128 KiB dynamic LDS for the 8-phase GEMM (host-side attr, capture-safe)
  (void)hipFuncSetAttribute((const void*)gemm256_bf16,
                            hipFuncAttributeMaxDynamicSharedMemorySize, 131072);

  dim3 blk(256);

  // input conversions
  convert_pad_x<<<dim3((B_SZ * KP1 + 255) / 256), blk, 0, stream>>>(x, xb);
  transpose_convert<<<dim3(H_DIM / 32, KP1 / 32), blk, 0, stream>>>(W1, w1t, D_IN, H_DIM, KP1);
  transpose_convert<<<dim3(H_DIM / 32, H_DIM / 32), blk, 0, stream>>>(W2, w2t, H_DIM, H_DIM, H_DIM);

  // layer 1: h1 = relu(xb @ w1t^T + b1)   [8192,896]x[896,4096]
  gemm256_bf16<<<dim3(H_DIM / 256, B_SZ / 256), dim3(512), 131072, stream>>>(
      xb, w1t, b1, h1, B_SZ, H_DIM, KP1);

  // layer 2: h2 = relu(h1 @ w2t^T + b2)   [8192,4096]x[4096,4096]
  gemm256_bf16<<<dim3(H_DIM / 256, B_SZ / 256), dim3(512), 131072, stream>>>(
      h1, w2t, b2, h2, B_SZ, H_DIM, H_DIM);

  // layer 3 + softmax -> probs
  logits_softmax_kernel<<<dim3(B_SZ / 4), blk, 0, stream>>>(h2, W3, b3, probs, B_SZ);

  // circuit eval -> out[B]
  circuit_kernel<<<dim3(B_SZ / 256), blk, 0, stream>>>(probs, out, B_SZ);
}

// Round 7
// 576.599 us; speedup vs baseline: 1.5466x; 1.5439x over previous
//
#include <hip/hip_runtime.h>
#include <cstdint>
#include <cstddef>

// ---------------------------------------------------------------------------
// Problem constants
// ---------------------------------------------------------------------------
constexpr int N_CLASSES  = 10;
constexpr int N_INTERNAL = 256;
constexpr int N_VALS     = 2 * N_CLASSES + N_INTERNAL;  // 276
constexpr int B_SZ  = 8192;
constexpr int D_IN  = 784;
constexpr int KP1   = 896;    // D_IN padded to multiple of 128 (8-phase needs K%128==0)
constexpr int H_DIM = 4096;

// ---------------------------------------------------------------------------
// Compile-time reconstruction of np.random.RandomState(0) circuit generation.
// (verified bit-exact in round 2: absmax == 0.0)
// ---------------------------------------------------------------------------
struct MTState {
  uint32_t key[624];
  int pos;
};

constexpr uint32_t mt_next(MTState& st) {
  if (st.pos == 624) {
    for (int i = 0; i < 624; ++i) {
      uint32_t y = (st.key[i] & 0x80000000u) | (st.key[(i + 1) % 624] & 0x7fffffffu);
      st.key[i] = st.key[(i + 397) % 624] ^ (y >> 1) ^ ((y & 1u) ? 0x9908b0dfu : 0u);
    }
    st.pos = 0;
  }
  uint32_t y = st.key[st.pos++];
  y ^= y >> 11;
  y ^= (y << 7) & 0x9d2c5680u;
  y ^= (y << 15) & 0xefc60000u;
  y ^= y >> 18;
  return y;
}

constexpr uint32_t interval_draw(MTState& st, uint32_t maxv) {
  if (maxv == 0u) return 0u;
  uint32_t mask = maxv;
  mask |= mask >> 1; mask |= mask >> 2; mask |= mask >> 4;
  mask |= mask >> 8; mask |= mask >> 16;
  uint32_t v = mt_next(st) & mask;
  while (v > maxv) v = mt_next(st) & mask;
  return v;
}

struct Circuit {
  int16_t prime[N_INTERNAL][3];
  int16_t sub[N_INTERNAL][3];
};

constexpr Circuit make_circuit() {
  MTState st{};
  uint32_t s = 0u;
  for (int i = 0; i < 624; ++i) {
    st.key[i] = s;
    s = 1812433253u * (s ^ (s >> 30)) + (uint32_t)i + 1u;
  }
  st.pos = 624;

  Circuit c{};
  for (int node = 0; node < N_INTERNAL; ++node) {
    const int avail = 2 * N_CLASSES + node;
    int arr[N_CLASSES] = {0, 1, 2, 3, 4, 5, 6, 7, 8, 9};
    for (int i = N_CLASSES - 1; i >= 1; --i) {
      uint32_t j = interval_draw(st, (uint32_t)i);
      int tmp = arr[i]; arr[i] = arr[j]; arr[j] = tmp;
    }
    for (int e = 0; e < 3; ++e) c.prime[node][e] = (int16_t)arr[e];
    for (int e = 0; e < 3; ++e) c.sub[node][e] = (int16_t)interval_draw(st, (uint32_t)(avail - 1));
  }
  return c;
}

constexpr Circuit CIRC = make_circuit();

// ---------------------------------------------------------------------------
// helpers
// ---------------------------------------------------------------------------
__device__ __forceinline__ uint16_t f2bf(float f) {
  uint32_t u = __builtin_bit_cast(uint32_t, f);
  uint32_t r = (u + 0x7fffu + ((u >> 16) & 1u)) >> 16;  // RNE
  return (uint16_t)r;
}
__device__ __forceinline__ float bf2f(uint16_t h) {
  uint32_t u = ((uint32_t)h) << 16;
  return __builtin_bit_cast(float, u);
}

__device__ __forceinline__ void load_lds16(const void* g, void* l) {
  __builtin_amdgcn_global_load_lds(
      (const __attribute__((address_space(1))) unsigned int*)g,
      (__attribute__((address_space(3))) unsigned int*)l, 16, 0, 0);
}

using bf16x8 = __attribute__((ext_vector_type(8))) short;
using f32x4  = __attribute__((ext_vector_type(4))) float;

__device__ __forceinline__ void dsr(bf16x8& d, uint32_t a) {
  asm volatile("ds_read_b128 %0, %1" : "=v"(d) : "v"(a));
}

// ---------------------------------------------------------------------------
// Circuit evaluation: fully unrolled, static indices only
// ---------------------------------------------------------------------------
template <int I>
__device__ __forceinline__ void eval_node(float (&vals)[N_VALS]) {
  if constexpr (I < N_INTERNAL) {
    constexpr int p0 = CIRC.prime[I][0], s0 = CIRC.sub[I][0];
    constexpr int p1 = CIRC.prime[I][1], s1 = CIRC.sub[I][1];
    constexpr int p2 = CIRC.prime[I][2], s2 = CIRC.sub[I][2];
    vals[2 * N_CLASSES + I] =
        vals[p0] * vals[s0] + vals[p1] * vals[s1] + vals[p2] * vals[s2];
    eval_node<I + 1>(vals);
  }
}

__global__ __launch_bounds__(256) void circuit_kernel(
    const float* __restrict__ probs, float* __restrict__ out, int B) {
  int r = blockIdx.x * blockDim.x + threadIdx.x;
  if (r >= B) return;
  float vals[N_VALS];
#pragma unroll
  for (int c = 0; c < N_CLASSES; ++c) {
    float p = probs[r * N_CLASSES + c];
    vals[c] = p;
    vals[N_CLASSES + c] = 1.0f - p;
  }
  eval_node<0>(vals);
  out[r] = vals[N_VALS - 1];
}

// ---------------------------------------------------------------------------
// x [B,784] f32 -> xb [B,896] bf16 (zero-padded)
// ---------------------------------------------------------------------------
__global__ __launch_bounds__(256) void convert_pad_x(
    const float* __restrict__ x, uint16_t* __restrict__ xb) {
  int idx = blockIdx.x * 256 + threadIdx.x;
  if (idx >= B_SZ * KP1) return;
  int r = idx / KP1, c = idx - r * KP1;
  xb[idx] = (c < D_IN) ? f2bf(x[(size_t)r * D_IN + c]) : (uint16_t)0;
}

// ---------------------------------------------------------------------------
// W [K,N] f32 -> Wt [N,Kp] bf16 (transpose + convert, zero-pad k in [K,Kp))
// ---------------------------------------------------------------------------
__global__ __launch_bounds__(256) void transpose_convert(
    const float* __restrict__ W, uint16_t* __restrict__ Wt,
    int K, int N, int Kp) {
  __shared__ float tile[32][33];
  const int kt = blockIdx.y * 32;
  const int nt = blockIdx.x * 32;
  const int tc = threadIdx.x & 31;
  const int tr = threadIdx.x >> 5;  // 0..7
#pragma unroll
  for (int i = 0; i < 4; ++i) {
    int k = kt + tr + i * 8;
    tile[tr + i * 8][tc] = (k < K) ? W[(size_t)k * N + nt + tc] : 0.0f;
  }
  __syncthreads();
#pragma unroll
  for (int i = 0; i < 4; ++i) {
    int n = nt + tr + i * 8;
    int k = kt + tc;
    if (k < Kp) Wt[(size_t)n * Kp + k] = f2bf(tile[tc][tr + i * 8]);
  }
}

// ---------------------------------------------------------------------------
// 256x256 8-phase bf16 MFMA GEMM (m201-style template):
//   C[M,N] = relu(A[M,K] @ Bt[N,K]^T + bias[N]), bf16 in/out, f32 accum.
// 512 threads = 8 waves (2Mx4N), per-wave 128x64 output. BK=64, 2 K-tiles/iter,
// 8 phases/iter, quadrant order (00),(01),(11),(10).
// Register budget is the binding constraint (R5/R6: allocator pins VGPR=128;
// exceeding it spills loop-invariant staging addresses -> +330MB FETCH, 2x dur):
//   - staging offsets are uint32 (8 VGPRs, not 16)
//   - Br is [2][2] (16 VGPRs): B0 is RE-READ from LDS in phase 4 instead of
//     held live for 3 phases. Reads/iter = 12/4/8/4 = 56 ds_read_b128 —
//     still under the MFMA critical path (3584+1024 cy < 4966 cy).
// Stage placement re-derived for the ph4 B0 re-read (B0 overwrite moves to
// ph5); one 2-load stage per phase; vmcnt(6) at phases 4/8 confirms exactly
// the next-read tile. LDS 128 KiB, row-permuted halves + slot^=(row&7) XOR
// swizzle; staging = linear LDS dest + inverse-swizzled per-lane source.
// Requires: M%256==0, N%256==0, K%128==0, K>=256.
// ---------------------------------------------------------------------------
template <int MH, int NH, bool RA, bool RB, int VM, typename F>
__device__ __forceinline__ void phase_t(
    uint32_t aB, uint32_t bB, uint32_t s0v, uint32_t s1v,
    bf16x8 (&Ar)[4][2], bf16x8 (&Br)[2][2][2], f32x4 (&acc)[2][2][4][2],
    F&& stage) {
  // 1. ds_read fragments (volatile asm — pinned within the phase's barriers)
  if constexpr (RA) {
#pragma unroll
    for (int m = 0; m < 4; ++m) {
      dsr(Ar[m][0], aB + MH * 16384 + m * 2048 + s0v);
      dsr(Ar[m][1], aB + MH * 16384 + m * 2048 + s1v);
    }
  }
  if constexpr (RB) {
#pragma unroll
    for (int nf = 0; nf < 2; ++nf) {
      dsr(Br[NH][nf][0], bB + NH * 16384 + nf * 2048 + s0v);
      dsr(Br[NH][nf][1], bB + NH * 16384 + nf * 2048 + s1v);
    }
  }
  // 2. stage issues (global_load_lds) for this phase
  stage();
  // 3. barrier; wait LDS reads; MFMA cluster
  __builtin_amdgcn_s_barrier();
  asm volatile("s_waitcnt lgkmcnt(0)" ::: "memory");
  __builtin_amdgcn_sched_barrier(0);  // rule #18: pin MFMAs below the wait
  __builtin_amdgcn_s_setprio(1);
#pragma unroll
  for (int m = 0; m < 4; ++m)
#pragma unroll
    for (int nf = 0; nf < 2; ++nf) {
      acc[MH][NH][m][nf] = __builtin_amdgcn_mfma_f32_16x16x32_bf16(
          Ar[m][0], Br[NH][nf][0], acc[MH][NH][m][nf], 0, 0, 0);
      acc[MH][NH][m][nf] = __builtin_amdgcn_mfma_f32_16x16x32_bf16(
          Ar[m][1], Br[NH][nf][1], acc[MH][NH][m][nf], 0, 0, 0);
    }
  __builtin_amdgcn_s_setprio(0);
  // 4. counted vmcnt (confirms the tile read after the NEXT barrier)
  if constexpr (VM >= 0) asm volatile("s_waitcnt vmcnt(%0)" :: "i"(VM) : "memory");
  __builtin_amdgcn_s_barrier();
}

__global__ __launch_bounds__(512, 1) void gemm256_bf16(
    const uint16_t* __restrict__ A, const uint16_t* __restrict__ Bt,
    const float* __restrict__ bias, uint16_t* __restrict__ C,
    int M, int N, int K) {
  extern __shared__ char smem[];

  const int t    = threadIdx.x;
  const int t16  = t * 16;
  const int lane = t & 63;
  const int wid  = t >> 6;
  const int wr   = wid >> 2;   // 0..1
  const int wc   = wid & 3;    // 0..3
  const int fr   = lane & 15;
  const int fq   = lane >> 4;

  // XCD-aware bijective swizzle (nwg % 8 == 0 for both layers)
  const int gx = gridDim.x, gy = gridDim.y;
  const int nwg = gx * gy;
  const int id  = blockIdx.y * gx + blockIdx.x;
  const int cpx = nwg >> 3;
  const int sid = (id & 7) * cpx + (id >> 3);
  const int row0 = (sid / gx) * 256;
  const int col0 = (sid % gx) * 256;

  const uint32_t Kb = (uint32_t)K * 2;
  const char* Ab = (const char*)A;
  const char* Bb = (const char*)Bt;

  // ---- per-thread staging source offsets, 32-bit (inverse swizzle + row perm)
  uint32_t srcA00, srcA01, srcA10, srcA11, srcB00, srcB01, srcB10, srcB11;
#define MKSRC(h, j, SA_, SB_) { \
    const int off_ = (j) * 8192 + t16; \
    const int p_ = (h) * 128 + (off_ >> 7); \
    const int s_ = (off_ >> 4) & 7, sg_ = s_ ^ (p_ & 7); \
    const int ga_ = (((p_ >> 6) & 1) * 128) + (h) * 64 + (p_ & 63); \
    const int gb_ = (((p_ >> 5) & 3) * 64) + (h) * 32 + (p_ & 31); \
    SA_ = (uint32_t)(row0 + ga_) * Kb + (uint32_t)(sg_ * 16); \
    SB_ = (uint32_t)(col0 + gb_) * Kb + (uint32_t)(sg_ * 16); }
  MKSRC(0, 0, srcA00, srcB00)
  MKSRC(0, 1, srcA01, srcB01)
  MKSRC(1, 0, srcA10, srcB10)
  MKSRC(1, 1, srcA11, srcB11)
#undef MKSRC

#define STAGE_A(v, h, kt) do { const char* g_ = Ab + (size_t)(kt) * 128; \
    load_lds16(g_ + srcA##h##0, smem + (v) * 32768 + (h) * 16384 + t16); \
    load_lds16(g_ + srcA##h##1, smem + (v) * 32768 + (h) * 16384 + 8192 + t16); } while (0)
#define STAGE_B(v, h, kt) do { const char* g_ = Bb + (size_t)(kt) * 128; \
    load_lds16(g_ + srcB##h##0, smem + 65536 + (v) * 32768 + (h) * 16384 + t16); \
    load_lds16(g_ + srcB##h##1, smem + 65536 + (v) * 32768 + (h) * 16384 + 8192 + t16); } while (0)

  // ---- per-thread ds_read bases (swizzled)
  const uint32_t smb = (uint32_t)(size_t)(__attribute__((address_space(3))) char*)smem;
  const uint32_t aB0 = smb + (uint32_t)((wr * 64 + fr) * 128);
  const uint32_t bB0 = smb + 65536u + (uint32_t)((wc * 32 + fr) * 128);
  const uint32_t s0v = (uint32_t)(((0 * 4 + fq) ^ (fr & 7)) * 16);
  const uint32_t s1v = (uint32_t)(((1 * 4 + fq) ^ (fr & 7)) * 16);

  f32x4 acc[2][2][4][2];
#pragma unroll
  for (int a = 0; a < 2; ++a)
#pragma unroll
    for (int b = 0; b < 2; ++b)
#pragma unroll
      for (int m = 0; m < 4; ++m)
#pragma unroll
        for (int n = 0; n < 2; ++n) {
          acc[a][b][m][n][0] = 0.f; acc[a][b][m][n][1] = 0.f;
          acc[a][b][m][n][2] = 0.f; acc[a][b][m][n][3] = 0.f;
        }

  bf16x8 Ar[4][2], Br[2][2][2];

  // ---- prologue: tile0 fully (8 loads); tile1 minus B0 (6 loads)
  STAGE_A(0, 0, 0); STAGE_B(0, 0, 0); STAGE_A(0, 1, 0); STAGE_B(0, 1, 0);
  STAGE_A(1, 0, 1); STAGE_B(1, 1, 1); STAGE_A(1, 1, 1);
  asm volatile("s_waitcnt vmcnt(6)" ::: "memory");
  __builtin_amdgcn_s_barrier();

#define PH(MH_, NH_, RA_, RB_, VM_, BUF_, ...) \
  phase_t<MH_, NH_, RA_, RB_, VM_>(aB0 + (BUF_) * 32768, bB0 + (BUF_) * 32768, \
                                   s0v, s1v, Ar, Br, acc, [&]() { __VA_ARGS__ })

  const int NI = K >> 7;  // iterations; 2 K-tiles each
  int i = 0;
  for (; i < NI - 1; ++i) {
    const int ktb = 2 * i + 1, ktc = 2 * i + 2, ktd = 2 * i + 3;
    PH(0, 0, true,  true,  -1, 0, STAGE_B(1, 0, ktb); );
    PH(0, 1, false, true,  -1, 0, STAGE_A(0, 0, ktc); );
    PH(1, 1, true,  false, -1, 0, STAGE_B(0, 1, ktc); );
    PH(1, 0, false, true,   6, 0, STAGE_A(0, 1, ktc); );
    PH(0, 0, true,  true,  -1, 1, STAGE_B(0, 0, ktc); );
    PH(0, 1, false, true,  -1, 1, STAGE_A(1, 0, ktd); );
    PH(1, 1, true,  false, -1, 1, STAGE_B(1, 1, ktd); );
    PH(1, 0, false, true,   6, 1, STAGE_A(1, 1, ktd); );
  }
  // peeled last iteration: stage only tile b's deferred B0, then drain
  {
    const int ktb = 2 * i + 1;
    PH(0, 0, true,  true,  -1, 0, STAGE_B(1, 0, ktb); );
    PH(0, 1, false, true,  -1, 0, );
    PH(1, 1, true,  false, -1, 0, );
    PH(1, 0, false, true,   0, 0, );
    PH(0, 0, true,  true,  -1, 1, );
    PH(0, 1, false, true,  -1, 1, );
    PH(1, 1, true,  false, -1, 1, );
    PH(1, 0, false, true,  -1, 1, );
  }
#undef PH
#undef STAGE_A
#undef STAGE_B

  // ---- epilogue: bias + relu + bf16 store
  // C/D layout: col = lane&15, row = (lane>>4)*4 + j   [measured m89]
#pragma unroll
  for (int mh = 0; mh < 2; ++mh)
#pragma unroll
    for (int nh = 0; nh < 2; ++nh)
#pragma unroll
      for (int m = 0; m < 4; ++m)
#pragma unroll
        for (int nf = 0; nf < 2; ++nf) {
          const int row = row0 + wr * 128 + mh * 64 + m * 16 + fq * 4;
          const int col = col0 + wc * 64 + nh * 32 + nf * 16 + fr;
          const float bv = bias[col];
          const size_t base = (size_t)row * N + col;
#pragma unroll
          for (int j = 0; j < 4; ++j) {
            float v = acc[mh][nh][m][nf][j] + bv;
            v = fmaxf(v, 0.0f);
            C[base + (size_t)j * N] = f2bf(v);
          }
        }
}

// ---------------------------------------------------------------------------
// logits (K=4096, N=10) + softmax -> probs[B,10]; one wave per row; h2 bf16
// ---------------------------------------------------------------------------
__global__ __launch_bounds__(256) void logits_softmax_kernel(
    const uint16_t* __restrict__ h2, const float* __restrict__ W3,
    const float* __restrict__ b3, float* __restrict__ probs, int B) {
  const int wave = threadIdx.x >> 6;
  const int lane = threadIdx.x & 63;
  const int row  = blockIdx.x * 4 + wave;
  if (row >= B) return;

  const uint16_t* hrow = h2 + (size_t)row * H_DIM;
  float acc[N_CLASSES];
#pragma unroll
  for (int c = 0; c < N_CLASSES; ++c) acc[c] = 0.0f;

#pragma unroll
  for (int it = 0; it < H_DIM / (64 * 8); ++it) {
    const int k0 = (it * 64 + lane) * 8;
    ushort4 u0 = *reinterpret_cast<const ushort4*>(hrow + k0);
    ushort4 u1 = *reinterpret_cast<const ushort4*>(hrow + k0 + 4);
    float hv[8] = {bf2f(u0.x), bf2f(u0.y), bf2f(u0.z), bf2f(u0.w),
                   bf2f(u1.x), bf2f(u1.y), bf2f(u1.z), bf2f(u1.w)};
#pragma unroll
    for (int q = 0; q < 8; ++q) {
      const float* wrow = W3 + (size_t)(k0 + q) * N_CLASSES;
#pragma unroll
      for (int c = 0; c < N_CLASSES; ++c) acc[c] = fmaf(hv[q], wrow[c], acc[c]);
    }
  }

#pragma unroll
  for (int c = 0; c < N_CLASSES; ++c) {
#pragma unroll
    for (int s = 32; s >= 1; s >>= 1) acc[c] += __shfl_xor(acc[c], s, 64);
  }

  if (lane == 0) {
    float l[N_CLASSES], m = -3.0e38f;
#pragma unroll
    for (int c = 0; c < N_CLASSES; ++c) {
      l[c] = acc[c] + b3[c];
      m = fmaxf(m, l[c]);
    }
    float sum = 0.0f;
#pragma unroll
    for (int c = 0; c < N_CLASSES; ++c) {
      l[c] = expf(l[c] - m);
      sum += l[c];
    }
    const float inv = 1.0f / sum;
#pragma unroll
    for (int c = 0; c < N_CLASSES; ++c) probs[row * N_CLASSES + c] = l[c] * inv;
  }
}

// ---------------------------------------------------------------------------
// launch.  ws layout (bf16 unless noted), total ~182 MB:
//   xb[8192*896] w1t[4096*896] w2t[4096*4096] h1[8192*4096] h2[8192*4096]
//   probs f32[8192*10]
// ---------------------------------------------------------------------------
extern "C" void kernel_launch(void* const* d_in, const int* in_sizes, int n_in,
                              void* d_out, int out_size, void* d_ws, size_t ws_size,
                              hipStream_t stream) {
  const float* x  = (const float*)d_in[0];
  const float* W1 = (const float*)d_in[1];
  const float* b1 = (const float*)d_in[2];
  const float* W2 = (const float*)d_in[3];
  const float* b2 = (const float*)d_in[4];
  const float* W3 = (const float*)d_in[5];
  const float* b3 = (const float*)d_in[6];
  float* out = (float*)d_out;

  uint16_t* xb  = (uint16_t*)d_ws;
  uint16_t* w1t = xb  + (size_t)B_SZ * KP1;
  uint16_t* w2t = w1t + (size_t)H_DIM * KP1;
  uint16_t* h1  = w2t + (size_t)H_DIM * H_DIM;
  uint16_t* h2  = h1  + (size_t)B_SZ * H_DIM;
  float* probs  = (float*)(h2 + (size_t)B_SZ * H_DIM);

  // allow 128 KiB dynamic LDS for the 8-phase GEMM (host-side attr, capture-safe)
  (void)hipFuncSetAttribute((const void*)gemm256_bf16,
                            hipFuncAttributeMaxDynamicSharedMemorySize, 131072);

  dim3 blk(256);

  // input conversions
  convert_pad_x<<<dim3((B_SZ * KP1 + 255) / 256), blk, 0, stream>>>(x, xb);
  transpose_convert<<<dim3(H_DIM / 32, KP1 / 32), blk, 0, stream>>>(W1, w1t, D_IN, H_DIM, KP1);
  transpose_convert<<<dim3(H_DIM / 32, H_DIM / 32), blk, 0, stream>>>(W2, w2t, H_DIM, H_DIM, H_DIM);

  // layer 1: h1 = relu(xb @ w1t^T + b1)   [8192,896]x[896,4096]
  gemm256_bf16<<<dim3(H_DIM / 256, B_SZ / 256), dim3(512), 131072, stream>>>(
      xb, w1t, b1, h1, B_SZ, H_DIM, KP1);

  // layer 2: h2 = relu(h1 @ w2t^T + b2)   [8192,4096]x[4096,4096]
  gemm256_bf16<<<dim3(H_DIM / 256, B_SZ / 256), dim3(512), 131072, stream>>>(
      h1, w2t, b2, h2, B_SZ, H_DIM, H_DIM);

  // layer 3 + softmax -> probs
  logits_softmax_kernel<<<dim3(B_SZ / 4), blk, 0, stream>>>(h2, W3, b3, probs, B_SZ);

  // circuit eval -> out[B]
  circuit_kernel<<<dim3(B_SZ / 256), blk, 0, stream>>>(probs, out, B_SZ);
}

// Round 8
// 425.982 us; speedup vs baseline: 2.0935x; 1.3536x over previous
//
#include <hip/hip_runtime.h>
#include <cstdint>
#include <cstddef>

// ---------------------------------------------------------------------------
// Problem constants
// ---------------------------------------------------------------------------
constexpr int N_CLASSES  = 10;
constexpr int N_INTERNAL = 256;
constexpr int N_VALS     = 2 * N_CLASSES + N_INTERNAL;  // 276
constexpr int B_SZ  = 8192;
constexpr int D_IN  = 784;
constexpr int KP1   = 896;    // D_IN padded to multiple of 128 (8-phase needs K%128==0)
constexpr int H_DIM = 4096;

// ---------------------------------------------------------------------------
// Compile-time reconstruction of np.random.RandomState(0) circuit generation.
// (verified bit-exact in round 2: absmax == 0.0)
// ---------------------------------------------------------------------------
struct MTState {
  uint32_t key[624];
  int pos;
};

constexpr uint32_t mt_next(MTState& st) {
  if (st.pos == 624) {
    for (int i = 0; i < 624; ++i) {
      uint32_t y = (st.key[i] & 0x80000000u) | (st.key[(i + 1) % 624] & 0x7fffffffu);
      st.key[i] = st.key[(i + 397) % 624] ^ (y >> 1) ^ ((y & 1u) ? 0x9908b0dfu : 0u);
    }
    st.pos = 0;
  }
  uint32_t y = st.key[st.pos++];
  y ^= y >> 11;
  y ^= (y << 7) & 0x9d2c5680u;
  y ^= (y << 15) & 0xefc60000u;
  y ^= y >> 18;
  return y;
}

constexpr uint32_t interval_draw(MTState& st, uint32_t maxv) {
  if (maxv == 0u) return 0u;
  uint32_t mask = maxv;
  mask |= mask >> 1; mask |= mask >> 2; mask |= mask >> 4;
  mask |= mask >> 8; mask |= mask >> 16;
  uint32_t v = mt_next(st) & mask;
  while (v > maxv) v = mt_next(st) & mask;
  return v;
}

struct Circuit {
  int16_t prime[N_INTERNAL][3];
  int16_t sub[N_INTERNAL][3];
};

constexpr Circuit make_circuit() {
  MTState st{};
  uint32_t s = 0u;
  for (int i = 0; i < 624; ++i) {
    st.key[i] = s;
    s = 1812433253u * (s ^ (s >> 30)) + (uint32_t)i + 1u;
  }
  st.pos = 624;

  Circuit c{};
  for (int node = 0; node < N_INTERNAL; ++node) {
    const int avail = 2 * N_CLASSES + node;
    int arr[N_CLASSES] = {0, 1, 2, 3, 4, 5, 6, 7, 8, 9};
    for (int i = N_CLASSES - 1; i >= 1; --i) {
      uint32_t j = interval_draw(st, (uint32_t)i);
      int tmp = arr[i]; arr[i] = arr[j]; arr[j] = tmp;
    }
    for (int e = 0; e < 3; ++e) c.prime[node][e] = (int16_t)arr[e];
    for (int e = 0; e < 3; ++e) c.sub[node][e] = (int16_t)interval_draw(st, (uint32_t)(avail - 1));
  }
  return c;
}

constexpr Circuit CIRC = make_circuit();

// ---------------------------------------------------------------------------
// helpers
// ---------------------------------------------------------------------------
__device__ __forceinline__ uint16_t f2bf(float f) {
  uint32_t u = __builtin_bit_cast(uint32_t, f);
  uint32_t r = (u + 0x7fffu + ((u >> 16) & 1u)) >> 16;  // RNE
  return (uint16_t)r;
}
__device__ __forceinline__ float bf2f(uint16_t h) {
  uint32_t u = ((uint32_t)h) << 16;
  return __builtin_bit_cast(float, u);
}

__device__ __forceinline__ void load_lds16(const void* g, void* l) {
  __builtin_amdgcn_global_load_lds(
      (const __attribute__((address_space(1))) unsigned int*)g,
      (__attribute__((address_space(3))) unsigned int*)l, 16, 0, 0);
}

using bf16x8 = __attribute__((ext_vector_type(8))) short;
using f32x4  = __attribute__((ext_vector_type(4))) float;

// ds_read_b128 with compile-time offset immediate (no per-read VALU addr math)
template <int IMM>
__device__ __forceinline__ void dsr_i(bf16x8& d, uint32_t a) {
  asm volatile("ds_read_b128 %0, %1 offset:%2" : "=v"(d) : "v"(a), "n"(IMM));
}

// ---------------------------------------------------------------------------
// Circuit evaluation: fully unrolled, static indices only
// ---------------------------------------------------------------------------
template <int I>
__device__ __forceinline__ void eval_node(float (&vals)[N_VALS]) {
  if constexpr (I < N_INTERNAL) {
    constexpr int p0 = CIRC.prime[I][0], s0 = CIRC.sub[I][0];
    constexpr int p1 = CIRC.prime[I][1], s1 = CIRC.sub[I][1];
    constexpr int p2 = CIRC.prime[I][2], s2 = CIRC.sub[I][2];
    vals[2 * N_CLASSES + I] =
        vals[p0] * vals[s0] + vals[p1] * vals[s1] + vals[p2] * vals[s2];
    eval_node<I + 1>(vals);
  }
}

__global__ __launch_bounds__(256) void circuit_kernel(
    const float* __restrict__ probs, float* __restrict__ out, int B) {
  int r = blockIdx.x * blockDim.x + threadIdx.x;
  if (r >= B) return;
  float vals[N_VALS];
#pragma unroll
  for (int c = 0; c < N_CLASSES; ++c) {
    float p = probs[r * N_CLASSES + c];
    vals[c] = p;
    vals[N_CLASSES + c] = 1.0f - p;
  }
  eval_node<0>(vals);
  out[r] = vals[N_VALS - 1];
}

// ---------------------------------------------------------------------------
// x [B,784] f32 -> xb [B,896] bf16 (zero-padded)
// ---------------------------------------------------------------------------
__global__ __launch_bounds__(256) void convert_pad_x(
    const float* __restrict__ x, uint16_t* __restrict__ xb) {
  int idx = blockIdx.x * 256 + threadIdx.x;
  if (idx >= B_SZ * KP1) return;
  int r = idx / KP1, c = idx - r * KP1;
  xb[idx] = (c < D_IN) ? f2bf(x[(size_t)r * D_IN + c]) : (uint16_t)0;
}

// ---------------------------------------------------------------------------
// W [K,N] f32 -> Wt [N,Kp] bf16 (transpose + convert, zero-pad k in [K,Kp))
// ---------------------------------------------------------------------------
__global__ __launch_bounds__(256) void transpose_convert(
    const float* __restrict__ W, uint16_t* __restrict__ Wt,
    int K, int N, int Kp) {
  __shared__ float tile[32][33];
  const int kt = blockIdx.y * 32;
  const int nt = blockIdx.x * 32;
  const int tc = threadIdx.x & 31;
  const int tr = threadIdx.x >> 5;  // 0..7
#pragma unroll
  for (int i = 0; i < 4; ++i) {
    int k = kt + tr + i * 8;
    tile[tr + i * 8][tc] = (k < K) ? W[(size_t)k * N + nt + tc] : 0.0f;
  }
  __syncthreads();
#pragma unroll
  for (int i = 0; i < 4; ++i) {
    int n = nt + tr + i * 8;
    int k = kt + tc;
    if (k < Kp) Wt[(size_t)n * Kp + k] = f2bf(tile[tc][tr + i * 8]);
  }
}

// ---------------------------------------------------------------------------
// 256x256 8-phase bf16 MFMA GEMM (m201-style template):
//   C[M,N] = relu(A[M,K] @ Bt[N,K]^T + bias[N]), bf16 in/out, f32 accum.
// 512 threads = 8 waves (2Mx4N), per-wave 128x64 output. BK=64, 2 K-tiles/iter,
// 8 phases/iter, quadrant order (00),(01),(11),(10); B0 re-read in phase 4
// (56 ds_read_b128/iter, under the MFMA critical path).
// VGPR-budget engineering (R5-R7: allocator pins 128; excess spills staging
// addrs -> +FETCH, slowdown):
//   - ds_read addresses: 4 VGPRs + 16-bit offset IMMEDIATES (BUF/MH/m folded
//     at compile time via template BUF) — zero VALU addressing in the loop
//   - staging source offsets: 2 VGPRs (srcA, srcB); the four (h,j) variants
//     differ by UNIFORM row deltas (A: {0,128,64,192}, B: {0,128,32,160} rows)
//     folded into the SGPR-side pointer
// Demand ~= 112 data + ~10 addressing < 128 -> no spill.
// LDS 128 KiB, row-permuted halves + slot^=(row&7) XOR swizzle; staging =
// linear LDS dest + inverse-swizzled per-lane source. Counted vmcnt(6) at
// phases 4/8 only. Requires: M%256==0, N%256==0, K%128==0, K>=256.
// ---------------------------------------------------------------------------
template <int MH, int NH, int BUF, bool RA, bool RB, int VM, typename F>
__device__ __forceinline__ void phase_t(
    uint32_t aA0, uint32_t aA1, uint32_t bA0, uint32_t bA1,
    bf16x8 (&Ar)[4][2], bf16x8 (&Br)[2][2][2], f32x4 (&acc)[2][2][4][2],
    F&& stage) {
  constexpr int AO = BUF * 32768 + MH * 16384;
  constexpr int BO = BUF * 32768 + NH * 16384;
  // 1. ds_read fragments (volatile asm — pinned within the phase's barriers)
  if constexpr (RA) {
    dsr_i<AO + 0 * 2048>(Ar[0][0], aA0); dsr_i<AO + 0 * 2048>(Ar[0][1], aA1);
    dsr_i<AO + 1 * 2048>(Ar[1][0], aA0); dsr_i<AO + 1 * 2048>(Ar[1][1], aA1);
    dsr_i<AO + 2 * 2048>(Ar[2][0], aA0); dsr_i<AO + 2 * 2048>(Ar[2][1], aA1);
    dsr_i<AO + 3 * 2048>(Ar[3][0], aA0); dsr_i<AO + 3 * 2048>(Ar[3][1], aA1);
  }
  if constexpr (RB) {
    dsr_i<BO + 0 * 2048>(Br[NH][0][0], bA0); dsr_i<BO + 0 * 2048>(Br[NH][0][1], bA1);
    dsr_i<BO + 1 * 2048>(Br[NH][1][0], bA0); dsr_i<BO + 1 * 2048>(Br[NH][1][1], bA1);
  }
  // 2. stage issues (global_load_lds) for this phase
  stage();
  // 3. barrier; wait LDS reads; MFMA cluster
  __builtin_amdgcn_s_barrier();
  asm volatile("s_waitcnt lgkmcnt(0)" ::: "memory");
  __builtin_amdgcn_sched_barrier(0);  // rule #18: pin MFMAs below the wait
  __builtin_amdgcn_s_setprio(1);
#pragma unroll
  for (int m = 0; m < 4; ++m)
#pragma unroll
    for (int nf = 0; nf < 2; ++nf) {
      acc[MH][NH][m][nf] = __builtin_amdgcn_mfma_f32_16x16x32_bf16(
          Ar[m][0], Br[NH][nf][0], acc[MH][NH][m][nf], 0, 0, 0);
      acc[MH][NH][m][nf] = __builtin_amdgcn_mfma_f32_16x16x32_bf16(
          Ar[m][1], Br[NH][nf][1], acc[MH][NH][m][nf], 0, 0, 0);
    }
  __builtin_amdgcn_s_setprio(0);
  // 4. counted vmcnt (confirms the tile read after the NEXT barrier)
  if constexpr (VM >= 0) asm volatile("s_waitcnt vmcnt(%0)" :: "i"(VM) : "memory");
  __builtin_amdgcn_s_barrier();
}

__global__ __launch_bounds__(512, 1) void gemm256_bf16(
    const uint16_t* __restrict__ A, const uint16_t* __restrict__ Bt,
    const float* __restrict__ bias, uint16_t* __restrict__ C,
    int M, int N, int K) {
  extern __shared__ char smem[];

  const int t    = threadIdx.x;
  const int t16  = t * 16;
  const int lane = t & 63;
  const int wid  = t >> 6;
  const int wr   = wid >> 2;   // 0..1
  const int wc   = wid & 3;    // 0..3
  const int fr   = lane & 15;
  const int fq   = lane >> 4;

  // XCD-aware bijective swizzle (nwg % 8 == 0 for both layers)
  const int gx = gridDim.x, gy = gridDim.y;
  const int nwg = gx * gy;
  const int id  = blockIdx.y * gx + blockIdx.x;
  const int cpx = nwg >> 3;
  const int sid = (id & 7) * cpx + (id >> 3);
  const int row0 = (sid / gx) * 256;
  const int col0 = (sid % gx) * 256;

  const uint32_t Kb = (uint32_t)K * 2;

  // uniform (SGPR) staging base pointers: fold row0/col0
  const char* gA = (const char*)A + (size_t)row0 * Kb;
  const char* gB = (const char*)Bt + (size_t)col0 * Kb;

  // per-lane staging source offsets (2 VGPRs): row = t>>3, slot sg
  const uint32_t prow = (uint32_t)(t >> 3);
  const uint32_t sg   = (uint32_t)(((t & 7) ^ (t >> 3)) & 7) * 16u;
  const uint32_t srcA = prow * Kb + sg;
  const uint32_t srcB = (prow + 32u * (prow >> 5)) * Kb + sg;

  // uniform row deltas for the (h,j) staging variants
#define ROWA(h, j) ((h) * 64 + (j) * 128)
#define ROWB(h, j) ((h) * 32 + (j) * 128)

#define STAGE_A(v, h, kt) do { \
    load_lds16(gA + (size_t)(kt) * 128 + (size_t)ROWA(h, 0) * Kb + srcA, \
               smem + (v) * 32768 + (h) * 16384 + t16); \
    load_lds16(gA + (size_t)(kt) * 128 + (size_t)ROWA(h, 1) * Kb + srcA, \
               smem + (v) * 32768 + (h) * 16384 + 8192 + t16); } while (0)
#define STAGE_B(v, h, kt) do { \
    load_lds16(gB + (size_t)(kt) * 128 + (size_t)ROWB(h, 0) * Kb + srcB, \
               smem + 65536 + (v) * 32768 + (h) * 16384 + t16); \
    load_lds16(gB + (size_t)(kt) * 128 + (size_t)ROWB(h, 1) * Kb + srcB, \
               smem + 65536 + (v) * 32768 + (h) * 16384 + 8192 + t16); } while (0)

  // ---- per-thread ds_read base addresses (4 VGPRs; swizzle slot folded in)
  const uint32_t smb = (uint32_t)(size_t)(__attribute__((address_space(3))) char*)smem;
  const uint32_t s0v = (uint32_t)(((fq) ^ (fr & 7)) * 16);
  const uint32_t aA0 = smb + (uint32_t)((wr * 64 + fr) * 128) + s0v;
  const uint32_t aA1 = smb + (uint32_t)((wr * 64 + fr) * 128) + (s0v ^ 64u);
  const uint32_t bA0 = smb + 65536u + (uint32_t)((wc * 32 + fr) * 128) + s0v;
  const uint32_t bA1 = smb + 65536u + (uint32_t)((wc * 32 + fr) * 128) + (s0v ^ 64u);

  f32x4 acc[2][2][4][2];
#pragma unroll
  for (int a = 0; a < 2; ++a)
#pragma unroll
    for (int b = 0; b < 2; ++b)
#pragma unroll
      for (int m = 0; m < 4; ++m)
#pragma unroll
        for (int n = 0; n < 2; ++n) {
          acc[a][b][m][n][0] = 0.f; acc[a][b][m][n][1] = 0.f;
          acc[a][b][m][n][2] = 0.f; acc[a][b][m][n][3] = 0.f;
        }

  bf16x8 Ar[4][2], Br[2][2][2];

  // ---- prologue: tile0 fully (8 loads); tile1 minus B0 (6 loads)
  STAGE_A(0, 0, 0); STAGE_B(0, 0, 0); STAGE_A(0, 1, 0); STAGE_B(0, 1, 0);
  STAGE_A(1, 0, 1); STAGE_B(1, 1, 1); STAGE_A(1, 1, 1);
  asm volatile("s_waitcnt vmcnt(6)" ::: "memory");
  __builtin_amdgcn_s_barrier();

#define PH(MH_, NH_, RA_, RB_, VM_, BUF_, ...) \
  phase_t<MH_, NH_, BUF_, RA_, RB_, VM_>(aA0, aA1, bA0, bA1, \
                                         Ar, Br, acc, [&]() { __VA_ARGS__ })

  const int NI = K >> 7;  // iterations; 2 K-tiles each
  int i = 0;
  for (; i < NI - 1; ++i) {
    const int ktb = 2 * i + 1, ktc = 2 * i + 2, ktd = 2 * i + 3;
    PH(0, 0, true,  true,  -1, 0, STAGE_B(1, 0, ktb); );
    PH(0, 1, false, true,  -1, 0, STAGE_A(0, 0, ktc); );
    PH(1, 1, true,  false, -1, 0, STAGE_B(0, 1, ktc); );
    PH(1, 0, false, true,   6, 0, STAGE_A(0, 1, ktc); );
    PH(0, 0, true,  true,  -1, 1, STAGE_B(0, 0, ktc); );
    PH(0, 1, false, true,  -1, 1, STAGE_A(1, 0, ktd); );
    PH(1, 1, true,  false, -1, 1, STAGE_B(1, 1, ktd); );
    PH(1, 0, false, true,   6, 1, STAGE_A(1, 1, ktd); );
  }
  // peeled last iteration: stage only tile b's deferred B0, then drain
  {
    const int ktb = 2 * i + 1;
    PH(0, 0, true,  true,  -1, 0, STAGE_B(1, 0, ktb); );
    PH(0, 1, false, true,  -1, 0, );
    PH(1, 1, true,  false, -1, 0, );
    PH(1, 0, false, true,   0, 0, );
    PH(0, 0, true,  true,  -1, 1, );
    PH(0, 1, false, true,  -1, 1, );
    PH(1, 1, true,  false, -1, 1, );
    PH(1, 0, false, true,  -1, 1, );
  }
#undef PH
#undef STAGE_A
#undef STAGE_B
#undef ROWA
#undef ROWB

  // ---- epilogue: bias + relu + bf16 store
  // C/D layout: col = lane&15, row = (lane>>4)*4 + j   [measured m89]
#pragma unroll
  for (int mh = 0; mh < 2; ++mh)
#pragma unroll
    for (int nh = 0; nh < 2; ++nh)
#pragma unroll
      for (int m = 0; m < 4; ++m)
#pragma unroll
        for (int nf = 0; nf < 2; ++nf) {
          const int row = row0 + wr * 128 + mh * 64 + m * 16 + fq * 4;
          const int col = col0 + wc * 64 + nh * 32 + nf * 16 + fr;
          const float bv = bias[col];
          const size_t base = (size_t)row * N + col;
#pragma unroll
          for (int j = 0; j < 4; ++j) {
            float v = acc[mh][nh][m][nf][j] + bv;
            v = fmaxf(v, 0.0f);
            C[base + (size_t)j * N] = f2bf(v);
          }
        }
}

// ---------------------------------------------------------------------------
// logits (K=4096, N=10) + softmax -> probs[B,10]; one wave per row; h2 bf16
// ---------------------------------------------------------------------------
__global__ __launch_bounds__(256) void logits_softmax_kernel(
    const uint16_t* __restrict__ h2, const float* __restrict__ W3,
    const float* __restrict__ b3, float* __restrict__ probs, int B) {
  const int wave = threadIdx.x >> 6;
  const int lane = threadIdx.x & 63;
  const int row  = blockIdx.x * 4 + wave;
  if (row >= B) return;

  const uint16_t* hrow = h2 + (size_t)row * H_DIM;
  float acc[N_CLASSES];
#pragma unroll
  for (int c = 0; c < N_CLASSES; ++c) acc[c] = 0.0f;

#pragma unroll
  for (int it = 0; it < H_DIM / (64 * 8); ++it) {
    const int k0 = (it * 64 + lane) * 8;
    ushort4 u0 = *reinterpret_cast<const ushort4*>(hrow + k0);
    ushort4 u1 = *reinterpret_cast<const ushort4*>(hrow + k0 + 4);
    float hv[8] = {bf2f(u0.x), bf2f(u0.y), bf2f(u0.z), bf2f(u0.w),
                   bf2f(u1.x), bf2f(u1.y), bf2f(u1.z), bf2f(u1.w)};
#pragma unroll
    for (int q = 0; q < 8; ++q) {
      const float* wrow = W3 + (size_t)(k0 + q) * N_CLASSES;
#pragma unroll
      for (int c = 0; c < N_CLASSES; ++c) acc[c] = fmaf(hv[q], wrow[c], acc[c]);
    }
  }

#pragma unroll
  for (int c = 0; c < N_CLASSES; ++c) {
#pragma unroll
    for (int s = 32; s >= 1; s >>= 1) acc[c] += __shfl_xor(acc[c], s, 64);
  }

  if (lane == 0) {
    float l[N_CLASSES], m = -3.0e38f;
#pragma unroll
    for (int c = 0; c < N_CLASSES; ++c) {
      l[c] = acc[c] + b3[c];
      m = fmaxf(m, l[c]);
    }
    float sum = 0.0f;
#pragma unroll
    for (int c = 0; c < N_CLASSES; ++c) {
      l[c] = expf(l[c] - m);
      sum += l[c];
    }
    const float inv = 1.0f / sum;
#pragma unroll
    for (int c = 0; c < N_CLASSES; ++c) probs[row * N_CLASSES + c] = l[c] * inv;
  }
}

// ---------------------------------------------------------------------------
// launch.  ws layout (bf16 unless noted), total ~182 MB:
//   xb[8192*896] w1t[4096*896] w2t[4096*4096] h1[8192*4096] h2[8192*4096]
//   probs f32[8192*10]
// ---------------------------------------------------------------------------
extern "C" void kernel_launch(void* const* d_in, const int* in_sizes, int n_in,
                              void* d_out, int out_size, void* d_ws, size_t ws_size,
                              hipStream_t stream) {
  const float* x  = (const float*)d_in[0];
  const float* W1 = (const float*)d_in[1];
  const float* b1 = (const float*)d_in[2];
  const float* W2 = (const float*)d_in[3];
  const float* b2 = (const float*)d_in[4];
  const float* W3 = (const float*)d_in[5];
  const float* b3 = (const float*)d_in[6];
  float* out = (float*)d_out;

  uint16_t* xb  = (uint16_t*)d_ws;
  uint16_t* w1t = xb  + (size_t)B_SZ * KP1;
  uint16_t* w2t = w1t + (size_t)H_DIM * KP1;
  uint16_t* h1  = w2t + (size_t)H_DIM * H_DIM;
  uint16_t* h2  = h1  + (size_t)B_SZ * H_DIM;
  float* probs  = (float*)(h2 + (size_t)B_SZ * H_DIM);

  // allow 128 KiB dynamic LDS for the 8-phase GEMM (host-side attr, capture-safe)
  (void)hipFuncSetAttribute((const void*)gemm256_bf16,
                            hipFuncAttributeMaxDynamicSharedMemorySize, 131072);

  dim3 blk(256);

  // input conversions
  convert_pad_x<<<dim3((B_SZ * KP1 + 255) / 256), blk, 0, stream>>>(x, xb);
  transpose_convert<<<dim3(H_DIM / 32, KP1 / 32), blk, 0, stream>>>(W1, w1t, D_IN, H_DIM, KP1);
  transpose_convert<<<dim3(H_DIM / 32, H_DIM / 32), blk, 0, stream>>>(W2, w2t, H_DIM, H_DIM, H_DIM);

  // layer 1: h1 = relu(xb @ w1t^T + b1)   [8192,896]x[896,4096]
  gemm256_bf16<<<dim3(H_DIM / 256, B_SZ / 256), dim3(512), 131072, stream>>>(
      xb, w1t, b1, h1, B_SZ, H_DIM, KP1);

  // layer 2: h2 = relu(h1 @ w2t^T + b2)   [8192,4096]x[4096,4096]
  gemm256_bf16<<<dim3(H_DIM / 256, B_SZ / 256), dim3(512), 131072, stream>>>(
      h1, w2t, b2, h2, B_SZ, H_DIM, H_DIM);

  // layer 3 + softmax -> probs
  logits_softmax_kernel<<<dim3(B_SZ / 4), blk, 0, stream>>>(h2, W3, b3, probs, B_SZ);

  // circuit eval -> out[B]
  circuit_kernel<<<dim3(B_SZ / 256), blk, 0, stream>>>(probs, out, B_SZ);
}

// Round 9
// 422.877 us; speedup vs baseline: 2.1089x; 1.0073x over previous
//
#include <hip/hip_runtime.h>
#include <cstdint>
#include <cstddef>

// ---------------------------------------------------------------------------
// Problem constants
// ---------------------------------------------------------------------------
constexpr int N_CLASSES  = 10;
constexpr int N_INTERNAL = 256;
constexpr int N_VALS     = 2 * N_CLASSES + N_INTERNAL;  // 276
constexpr int B_SZ  = 8192;
constexpr int D_IN  = 784;
constexpr int KP1   = 896;    // D_IN padded to multiple of 128 (8-phase needs K%128==0)
constexpr int H_DIM = 4096;

// ---------------------------------------------------------------------------
// Compile-time reconstruction of np.random.RandomState(0) circuit generation.
// (verified bit-exact in round 2: absmax == 0.0)
// ---------------------------------------------------------------------------
struct MTState {
  uint32_t key[624];
  int pos;
};

constexpr uint32_t mt_next(MTState& st) {
  if (st.pos == 624) {
    for (int i = 0; i < 624; ++i) {
      uint32_t y = (st.key[i] & 0x80000000u) | (st.key[(i + 1) % 624] & 0x7fffffffu);
      st.key[i] = st.key[(i + 397) % 624] ^ (y >> 1) ^ ((y & 1u) ? 0x9908b0dfu : 0u);
    }
    st.pos = 0;
  }
  uint32_t y = st.key[st.pos++];
  y ^= y >> 11;
  y ^= (y << 7) & 0x9d2c5680u;
  y ^= (y << 15) & 0xefc60000u;
  y ^= y >> 18;
  return y;
}

constexpr uint32_t interval_draw(MTState& st, uint32_t maxv) {
  if (maxv == 0u) return 0u;
  uint32_t mask = maxv;
  mask |= mask >> 1; mask |= mask >> 2; mask |= mask >> 4;
  mask |= mask >> 8; mask |= mask >> 16;
  uint32_t v = mt_next(st) & mask;
  while (v > maxv) v = mt_next(st) & mask;
  return v;
}

struct Circuit {
  int16_t prime[N_INTERNAL][3];
  int16_t sub[N_INTERNAL][3];
};

constexpr Circuit make_circuit() {
  MTState st{};
  uint32_t s = 0u;
  for (int i = 0; i < 624; ++i) {
    st.key[i] = s;
    s = 1812433253u * (s ^ (s >> 30)) + (uint32_t)i + 1u;
  }
  st.pos = 624;

  Circuit c{};
  for (int node = 0; node < N_INTERNAL; ++node) {
    const int avail = 2 * N_CLASSES + node;
    int arr[N_CLASSES] = {0, 1, 2, 3, 4, 5, 6, 7, 8, 9};
    for (int i = N_CLASSES - 1; i >= 1; --i) {
      uint32_t j = interval_draw(st, (uint32_t)i);
      int tmp = arr[i]; arr[i] = arr[j]; arr[j] = tmp;
    }
    for (int e = 0; e < 3; ++e) c.prime[node][e] = (int16_t)arr[e];
    for (int e = 0; e < 3; ++e) c.sub[node][e] = (int16_t)interval_draw(st, (uint32_t)(avail - 1));
  }
  return c;
}

constexpr Circuit CIRC = make_circuit();

// ---------------------------------------------------------------------------
// helpers
// ---------------------------------------------------------------------------
__device__ __forceinline__ uint16_t f2bf(float f) {
  uint32_t u = __builtin_bit_cast(uint32_t, f);
  uint32_t r = (u + 0x7fffu + ((u >> 16) & 1u)) >> 16;  // RNE
  return (uint16_t)r;
}
__device__ __forceinline__ float bf2f(uint16_t h) {
  uint32_t u = ((uint32_t)h) << 16;
  return __builtin_bit_cast(float, u);
}

__device__ __forceinline__ void load_lds16(const void* g, void* l) {
  __builtin_amdgcn_global_load_lds(
      (const __attribute__((address_space(1))) unsigned int*)g,
      (__attribute__((address_space(3))) unsigned int*)l, 16, 0, 0);
}

using bf16x8 = __attribute__((ext_vector_type(8))) short;
using f32x4  = __attribute__((ext_vector_type(4))) float;

// ds_read_b128 with compile-time offset immediate (no per-read VALU addr math)
template <int IMM>
__device__ __forceinline__ void dsr_i(bf16x8& d, uint32_t a) {
  asm volatile("ds_read_b128 %0, %1 offset:%2" : "=v"(d) : "v"(a), "n"(IMM));
}

// ---------------------------------------------------------------------------
// Circuit evaluation: fully unrolled, static indices only
// ---------------------------------------------------------------------------
template <int I>
__device__ __forceinline__ void eval_node(float (&vals)[N_VALS]) {
  if constexpr (I < N_INTERNAL) {
    constexpr int p0 = CIRC.prime[I][0], s0 = CIRC.sub[I][0];
    constexpr int p1 = CIRC.prime[I][1], s1 = CIRC.sub[I][1];
    constexpr int p2 = CIRC.prime[I][2], s2 = CIRC.sub[I][2];
    vals[2 * N_CLASSES + I] =
        vals[p0] * vals[s0] + vals[p1] * vals[s1] + vals[p2] * vals[s2];
    eval_node<I + 1>(vals);
  }
}

__global__ __launch_bounds__(256) void circuit_kernel(
    const float* __restrict__ probs, float* __restrict__ out, int B) {
  int r = blockIdx.x * blockDim.x + threadIdx.x;
  if (r >= B) return;
  float vals[N_VALS];
#pragma unroll
  for (int c = 0; c < N_CLASSES; ++c) {
    float p = probs[r * N_CLASSES + c];
    vals[c] = p;
    vals[N_CLASSES + c] = 1.0f - p;
  }
  eval_node<0>(vals);
  out[r] = vals[N_VALS - 1];
}

// ---------------------------------------------------------------------------
// x [B,784] f32 -> xb [B,896] bf16 (zero-padded)
// ---------------------------------------------------------------------------
__global__ __launch_bounds__(256) void convert_pad_x(
    const float* __restrict__ x, uint16_t* __restrict__ xb) {
  int idx = blockIdx.x * 256 + threadIdx.x;
  if (idx >= B_SZ * KP1) return;
  int r = idx / KP1, c = idx - r * KP1;
  xb[idx] = (c < D_IN) ? f2bf(x[(size_t)r * D_IN + c]) : (uint16_t)0;
}

// ---------------------------------------------------------------------------
// W [K,N] f32 -> Wt [N,Kp] bf16 (transpose + convert, zero-pad k in [K,Kp))
// ---------------------------------------------------------------------------
__global__ __launch_bounds__(256) void transpose_convert(
    const float* __restrict__ W, uint16_t* __restrict__ Wt,
    int K, int N, int Kp) {
  __shared__ float tile[32][33];
  const int kt = blockIdx.y * 32;
  const int nt = blockIdx.x * 32;
  const int tc = threadIdx.x & 31;
  const int tr = threadIdx.x >> 5;  // 0..7
#pragma unroll
  for (int i = 0; i < 4; ++i) {
    int k = kt + tr + i * 8;
    tile[tr + i * 8][tc] = (k < K) ? W[(size_t)k * N + nt + tc] : 0.0f;
  }
  __syncthreads();
#pragma unroll
  for (int i = 0; i < 4; ++i) {
    int n = nt + tr + i * 8;
    int k = kt + tc;
    if (k < Kp) Wt[(size_t)n * Kp + k] = f2bf(tile[tc][tr + i * 8]);
  }
}

// ---------------------------------------------------------------------------
// 256x256 8-phase bf16 MFMA GEMM (m201-style template, single-barrier phases):
//   C[M,N] = relu(A[M,K] @ Bt[N,K]^T + bias[N]), bf16 in/out, f32 accum.
// 512 threads = 8 waves (2Mx4N), per-wave 128x64 output. BK=64, 2 K-tiles/iter,
// 8 phases/iter, quadrant order (00),(01),(11),(10); B0 re-read in phase 4.
// ONE barrier per phase (post-MFMA). Safety: (a) stage-vs-read WAR — a staged
// region's last reader drained via its own lgkmcnt(0) before the PREVIOUS
// post-MFMA barrier, which the staging wave has already passed; (b) RAW —
// vmcnt(6) is per-wave self-confirmation before the barrier. The pre-MFMA
// barrier (R8) only enforced phase-lockstep; removing it halves barrier count
// and lets one wave's ds_reads overlap another's MFMA on the same SIMD.
// VGPR budget (R5-R8: allocator pins 128; excess spills -> +FETCH, 2x dur):
// ds_read addrs = 4 VGPRs + offset immediates; staging offsets = 2 VGPRs
// (uniform row deltas folded into SGPR pointer). Demand ~122 < 128.
// LDS 128 KiB, row-permuted halves + slot^=(row&7) XOR swizzle; staging =
// linear LDS dest + inverse-swizzled per-lane source. Counted vmcnt(6) at
// phases 4/8 only. Requires: M%256==0, N%256==0, K%128==0, K>=256.
// ---------------------------------------------------------------------------
template <int MH, int NH, int BUF, bool RA, bool RB, int VM, typename F>
__device__ __forceinline__ void phase_t(
    uint32_t aA0, uint32_t aA1, uint32_t bA0, uint32_t bA1,
    bf16x8 (&Ar)[4][2], bf16x8 (&Br)[2][2][2], f32x4 (&acc)[2][2][4][2],
    F&& stage) {
  constexpr int AO = BUF * 32768 + MH * 16384;
  constexpr int BO = BUF * 32768 + NH * 16384;
  // 1. ds_read fragments (volatile asm — pinned within the phase's barriers)
  if constexpr (RA) {
    dsr_i<AO + 0 * 2048>(Ar[0][0], aA0); dsr_i<AO + 0 * 2048>(Ar[0][1], aA1);
    dsr_i<AO + 1 * 2048>(Ar[1][0], aA0); dsr_i<AO + 1 * 2048>(Ar[1][1], aA1);
    dsr_i<AO + 2 * 2048>(Ar[2][0], aA0); dsr_i<AO + 2 * 2048>(Ar[2][1], aA1);
    dsr_i<AO + 3 * 2048>(Ar[3][0], aA0); dsr_i<AO + 3 * 2048>(Ar[3][1], aA1);
  }
  if constexpr (RB) {
    dsr_i<BO + 0 * 2048>(Br[NH][0][0], bA0); dsr_i<BO + 0 * 2048>(Br[NH][0][1], bA1);
    dsr_i<BO + 1 * 2048>(Br[NH][1][0], bA0); dsr_i<BO + 1 * 2048>(Br[NH][1][1], bA1);
  }
  // 2. stage issues (global_load_lds) for this phase
  stage();
  // 3. wait own LDS reads; MFMA cluster (no pre-MFMA barrier)
  asm volatile("s_waitcnt lgkmcnt(0)" ::: "memory");
  __builtin_amdgcn_sched_barrier(0);  // rule #18: pin MFMAs below the wait
  __builtin_amdgcn_s_setprio(1);
#pragma unroll
  for (int m = 0; m < 4; ++m)
#pragma unroll
    for (int nf = 0; nf < 2; ++nf) {
      acc[MH][NH][m][nf] = __builtin_amdgcn_mfma_f32_16x16x32_bf16(
          Ar[m][0], Br[NH][nf][0], acc[MH][NH][m][nf], 0, 0, 0);
      acc[MH][NH][m][nf] = __builtin_amdgcn_mfma_f32_16x16x32_bf16(
          Ar[m][1], Br[NH][nf][1], acc[MH][NH][m][nf], 0, 0, 0);
    }
  __builtin_amdgcn_s_setprio(0);
  // 4. counted vmcnt (confirms the tile read after the NEXT barrier)
  if constexpr (VM >= 0) asm volatile("s_waitcnt vmcnt(%0)" :: "i"(VM) : "memory");
  __builtin_amdgcn_s_barrier();
}

__global__ __launch_bounds__(512, 1) void gemm256_bf16(
    const uint16_t* __restrict__ A, const uint16_t* __restrict__ Bt,
    const float* __restrict__ bias, uint16_t* __restrict__ C,
    int M, int N, int K) {
  extern __shared__ char smem[];

  const int t    = threadIdx.x;
  const int t16  = t * 16;
  const int lane = t & 63;
  const int wid  = t >> 6;
  const int wr   = wid >> 2;   // 0..1
  const int wc   = wid & 3;    // 0..3
  const int fr   = lane & 15;
  const int fq   = lane >> 4;

  // XCD-aware bijective swizzle (nwg % 8 == 0 for both layers)
  const int gx = gridDim.x, gy = gridDim.y;
  const int nwg = gx * gy;
  const int id  = blockIdx.y * gx + blockIdx.x;
  const int cpx = nwg >> 3;
  const int sid = (id & 7) * cpx + (id >> 3);
  const int row0 = (sid / gx) * 256;
  const int col0 = (sid % gx) * 256;

  const uint32_t Kb = (uint32_t)K * 2;

  // uniform (SGPR) staging base pointers: fold row0/col0
  const char* gA = (const char*)A + (size_t)row0 * Kb;
  const char* gB = (const char*)Bt + (size_t)col0 * Kb;

  // per-lane staging source offsets (2 VGPRs): row = t>>3, slot sg
  const uint32_t prow = (uint32_t)(t >> 3);
  const uint32_t sg   = (uint32_t)(((t & 7) ^ (t >> 3)) & 7) * 16u;
  const uint32_t srcA = prow * Kb + sg;
  const uint32_t srcB = (prow + 32u * (prow >> 5)) * Kb + sg;

  // uniform row deltas for the (h,j) staging variants
#define ROWA(h, j) ((h) * 64 + (j) * 128)
#define ROWB(h, j) ((h) * 32 + (j) * 128)

#define STAGE_A(v, h, kt) do { \
    load_lds16(gA + (size_t)(kt) * 128 + (size_t)ROWA(h, 0) * Kb + srcA, \
               smem + (v) * 32768 + (h) * 16384 + t16); \
    load_lds16(gA + (size_t)(kt) * 128 + (size_t)ROWA(h, 1) * Kb + srcA, \
               smem + (v) * 32768 + (h) * 16384 + 8192 + t16); } while (0)
#define STAGE_B(v, h, kt) do { \
    load_lds16(gB + (size_t)(kt) * 128 + (size_t)ROWB(h, 0) * Kb + srcB, \
               smem + 65536 + (v) * 32768 + (h) * 16384 + t16); \
    load_lds16(gB + (size_t)(kt) * 128 + (size_t)ROWB(h, 1) * Kb + srcB, \
               smem + 65536 + (v) * 32768 + (h) * 16384 + 8192 + t16); } while (0)

  // ---- per-thread ds_read base addresses (4 VGPRs; swizzle slot folded in)
  const uint32_t smb = (uint32_t)(size_t)(__attribute__((address_space(3))) char*)smem;
  const uint32_t s0v = (uint32_t)(((fq) ^ (fr & 7)) * 16);
  const uint32_t aA0 = smb + (uint32_t)((wr * 64 + fr) * 128) + s0v;
  const uint32_t aA1 = smb + (uint32_t)((wr * 64 + fr) * 128) + (s0v ^ 64u);
  const uint32_t bA0 = smb + 65536u + (uint32_t)((wc * 32 + fr) * 128) + s0v;
  const uint32_t bA1 = smb + 65536u + (uint32_t)((wc * 32 + fr) * 128) + (s0v ^ 64u);

  f32x4 acc[2][2][4][2];
#pragma unroll
  for (int a = 0; a < 2; ++a)
#pragma unroll
    for (int b = 0; b < 2; ++b)
#pragma unroll
      for (int m = 0; m < 4; ++m)
#pragma unroll
        for (int n = 0; n < 2; ++n) {
          acc[a][b][m][n][0] = 0.f; acc[a][b][m][n][1] = 0.f;
          acc[a][b][m][n][2] = 0.f; acc[a][b][m][n][3] = 0.f;
        }

  bf16x8 Ar[4][2], Br[2][2][2];

  // ---- prologue: tile0 fully (8 loads); tile1 minus B0 (6 loads)
  STAGE_A(0, 0, 0); STAGE_B(0, 0, 0); STAGE_A(0, 1, 0); STAGE_B(0, 1, 0);
  STAGE_A(1, 0, 1); STAGE_B(1, 1, 1); STAGE_A(1, 1, 1);
  asm volatile("s_waitcnt vmcnt(6)" ::: "memory");
  __builtin_amdgcn_s_barrier();

#define PH(MH_, NH_, RA_, RB_, VM_, BUF_, ...) \
  phase_t<MH_, NH_, BUF_, RA_, RB_, VM_>(aA0, aA1, bA0, bA1, \
                                         Ar, Br, acc, [&]() { __VA_ARGS__ })

  const int NI = K >> 7;  // iterations; 2 K-tiles each
  int i = 0;
  for (; i < NI - 1; ++i) {
    const int ktb = 2 * i + 1, ktc = 2 * i + 2, ktd = 2 * i + 3;
    PH(0, 0, true,  true,  -1, 0, STAGE_B(1, 0, ktb); );
    PH(0, 1, false, true,  -1, 0, STAGE_A(0, 0, ktc); );
    PH(1, 1, true,  false, -1, 0, STAGE_B(0, 1, ktc); );
    PH(1, 0, false, true,   6, 0, STAGE_A(0, 1, ktc); );
    PH(0, 0, true,  true,  -1, 1, STAGE_B(0, 0, ktc); );
    PH(0, 1, false, true,  -1, 1, STAGE_A(1, 0, ktd); );
    PH(1, 1, true,  false, -1, 1, STAGE_B(1, 1, ktd); );
    PH(1, 0, false, true,   6, 1, STAGE_A(1, 1, ktd); );
  }
  // peeled last iteration: stage only tile b's deferred B0, then drain
  {
    const int ktb = 2 * i + 1;
    PH(0, 0, true,  true,  -1, 0, STAGE_B(1, 0, ktb); );
    PH(0, 1, false, true,  -1, 0, );
    PH(1, 1, true,  false, -1, 0, );
    PH(1, 0, false, true,   0, 0, );
    PH(0, 0, true,  true,  -1, 1, );
    PH(0, 1, false, true,  -1, 1, );
    PH(1, 1, true,  false, -1, 1, );
    PH(1, 0, false, true,  -1, 1, );
  }
#undef PH
#undef STAGE_A
#undef STAGE_B
#undef ROWA
#undef ROWB

  // ---- epilogue: bias + relu + bf16 store
  // C/D layout: col = lane&15, row = (lane>>4)*4 + j   [measured m89]
#pragma unroll
  for (int mh = 0; mh < 2; ++mh)
#pragma unroll
    for (int nh = 0; nh < 2; ++nh)
#pragma unroll
      for (int m = 0; m < 4; ++m)
#pragma unroll
        for (int nf = 0; nf < 2; ++nf) {
          const int row = row0 + wr * 128 + mh * 64 + m * 16 + fq * 4;
          const int col = col0 + wc * 64 + nh * 32 + nf * 16 + fr;
          const float bv = bias[col];
          const size_t base = (size_t)row * N + col;
#pragma unroll
          for (int j = 0; j < 4; ++j) {
            float v = acc[mh][nh][m][nf][j] + bv;
            v = fmaxf(v, 0.0f);
            C[base + (size_t)j * N] = f2bf(v);
          }
        }
}

// ---------------------------------------------------------------------------
// logits (K=4096, N=10) + softmax -> probs[B,10]; one wave per row; h2 bf16
// ---------------------------------------------------------------------------
__global__ __launch_bounds__(256) void logits_softmax_kernel(
    const uint16_t* __restrict__ h2, const float* __restrict__ W3,
    const float* __restrict__ b3, float* __restrict__ probs, int B) {
  const int wave = threadIdx.x >> 6;
  const int lane = threadIdx.x & 63;
  const int row  = blockIdx.x * 4 + wave;
  if (row >= B) return;

  const uint16_t* hrow = h2 + (size_t)row * H_DIM;
  float acc[N_CLASSES];
#pragma unroll
  for (int c = 0; c < N_CLASSES; ++c) acc[c] = 0.0f;

#pragma unroll
  for (int it = 0; it < H_DIM / (64 * 8); ++it) {
    const int k0 = (it * 64 + lane) * 8;
    ushort4 u0 = *reinterpret_cast<const ushort4*>(hrow + k0);
    ushort4 u1 = *reinterpret_cast<const ushort4*>(hrow + k0 + 4);
    float hv[8] = {bf2f(u0.x), bf2f(u0.y), bf2f(u0.z), bf2f(u0.w),
                   bf2f(u1.x), bf2f(u1.y), bf2f(u1.z), bf2f(u1.w)};
#pragma unroll
    for (int q = 0; q < 8; ++q) {
      const float* wrow = W3 + (size_t)(k0 + q) * N_CLASSES;
#pragma unroll
      for (int c = 0; c < N_CLASSES; ++c) acc[c] = fmaf(hv[q], wrow[c], acc[c]);
    }
  }

#pragma unroll
  for (int c = 0; c < N_CLASSES; ++c) {
#pragma unroll
    for (int s = 32; s >= 1; s >>= 1) acc[c] += __shfl_xor(acc[c], s, 64);
  }

  if (lane == 0) {
    float l[N_CLASSES], m = -3.0e38f;
#pragma unroll
    for (int c = 0; c < N_CLASSES; ++c) {
      l[c] = acc[c] + b3[c];
      m = fmaxf(m, l[c]);
    }
    float sum = 0.0f;
#pragma unroll
    for (int c = 0; c < N_CLASSES; ++c) {
      l[c] = expf(l[c] - m);
      sum += l[c];
    }
    const float inv = 1.0f / sum;
#pragma unroll
    for (int c = 0; c < N_CLASSES; ++c) probs[row * N_CLASSES + c] = l[c] * inv;
  }
}

// ---------------------------------------------------------------------------
// launch.  ws layout (bf16 unless noted), total ~182 MB:
//   xb[8192*896] w1t[4096*896] w2t[4096*4096] h1[8192*4096] h2[8192*4096]
//   probs f32[8192*10]
// ---------------------------------------------------------------------------
extern "C" void kernel_launch(void* const* d_in, const int* in_sizes, int n_in,
                              void* d_out, int out_size, void* d_ws, size_t ws_size,
                              hipStream_t stream) {
  const float* x  = (const float*)d_in[0];
  const float* W1 = (const float*)d_in[1];
  const float* b1 = (const float*)d_in[2];
  const float* W2 = (const float*)d_in[3];
  const float* b2 = (const float*)d_in[4];
  const float* W3 = (const float*)d_in[5];
  const float* b3 = (const float*)d_in[6];
  float* out = (float*)d_out;

  uint16_t* xb  = (uint16_t*)d_ws;
  uint16_t* w1t = xb  + (size_t)B_SZ * KP1;
  uint16_t* w2t = w1t + (size_t)H_DIM * KP1;
  uint16_t* h1  = w2t + (size_t)H_DIM * H_DIM;
  uint16_t* h2  = h1  + (size_t)B_SZ * H_DIM;
  float* probs  = (float*)(h2 + (size_t)B_SZ * H_DIM);

  // allow 128 KiB dynamic LDS for the 8-phase GEMM (host-side attr, capture-safe)
  (void)hipFuncSetAttribute((const void*)gemm256_bf16,
                            hipFuncAttributeMaxDynamicSharedMemorySize, 131072);

  dim3 blk(256);

  // input conversions
  convert_pad_x<<<dim3((B_SZ * KP1 + 255) / 256), blk, 0, stream>>>(x, xb);
  transpose_convert<<<dim3(H_DIM / 32, KP1 / 32), blk, 0, stream>>>(W1, w1t, D_IN, H_DIM, KP1);
  transpose_convert<<<dim3(H_DIM / 32, H_DIM / 32), blk, 0, stream>>>(W2, w2t, H_DIM, H_DIM, H_DIM);

  // layer 1: h1 = relu(xb @ w1t^T + b1)   [8192,896]x[896,4096]
  gemm256_bf16<<<dim3(H_DIM / 256, B_SZ / 256), dim3(512), 131072, stream>>>(
      xb, w1t, b1, h1, B_SZ, H_DIM, KP1);

  // layer 2: h2 = relu(h1 @ w2t^T + b2)   [8192,4096]x[4096,4096]
  gemm256_bf16<<<dim3(H_DIM / 256, B_SZ / 256), dim3(512), 131072, stream>>>(
      h1, w2t, b2, h2, B_SZ, H_DIM, H_DIM);

  // layer 3 + softmax -> probs
  logits_softmax_kernel<<<dim3(B_SZ / 4), blk, 0, stream>>>(h2, W3, b3, probs, B_SZ);

  // circuit eval -> out[B]
  circuit_kernel<<<dim3(B_SZ / 256), blk, 0, stream>>>(probs, out, B_SZ);
}

// Round 10
// 402.560 us; speedup vs baseline: 2.2153x; 1.0505x over previous
//
#include <hip/hip_runtime.h>
#include <cstdint>
#include <cstddef>

// ---------------------------------------------------------------------------
// Problem constants
// ---------------------------------------------------------------------------
constexpr int N_CLASSES  = 10;
constexpr int N_INTERNAL = 256;
constexpr int N_VALS     = 2 * N_CLASSES + N_INTERNAL;  // 276
constexpr int B_SZ  = 8192;
constexpr int D_IN  = 784;
constexpr int KP1   = 896;    // D_IN padded to multiple of 128 (8-phase needs K%128==0)
constexpr int H_DIM = 4096;

// ---------------------------------------------------------------------------
// Compile-time reconstruction of np.random.RandomState(0) circuit generation.
// (verified bit-exact in round 2: absmax == 0.0)
// ---------------------------------------------------------------------------
struct MTState {
  uint32_t key[624];
  int pos;
};

constexpr uint32_t mt_next(MTState& st) {
  if (st.pos == 624) {
    for (int i = 0; i < 624; ++i) {
      uint32_t y = (st.key[i] & 0x80000000u) | (st.key[(i + 1) % 624] & 0x7fffffffu);
      st.key[i] = st.key[(i + 397) % 624] ^ (y >> 1) ^ ((y & 1u) ? 0x9908b0dfu : 0u);
    }
    st.pos = 0;
  }
  uint32_t y = st.key[st.pos++];
  y ^= y >> 11;
  y ^= (y << 7) & 0x9d2c5680u;
  y ^= (y << 15) & 0xefc60000u;
  y ^= y >> 18;
  return y;
}

constexpr uint32_t interval_draw(MTState& st, uint32_t maxv) {
  if (maxv == 0u) return 0u;
  uint32_t mask = maxv;
  mask |= mask >> 1; mask |= mask >> 2; mask |= mask >> 4;
  mask |= mask >> 8; mask |= mask >> 16;
  uint32_t v = mt_next(st) & mask;
  while (v > maxv) v = mt_next(st) & mask;
  return v;
}

struct Circuit {
  int16_t prime[N_INTERNAL][3];
  int16_t sub[N_INTERNAL][3];
};

constexpr Circuit make_circuit() {
  MTState st{};
  uint32_t s = 0u;
  for (int i = 0; i < 624; ++i) {
    st.key[i] = s;
    s = 1812433253u * (s ^ (s >> 30)) + (uint32_t)i + 1u;
  }
  st.pos = 624;

  Circuit c{};
  for (int node = 0; node < N_INTERNAL; ++node) {
    const int avail = 2 * N_CLASSES + node;
    int arr[N_CLASSES] = {0, 1, 2, 3, 4, 5, 6, 7, 8, 9};
    for (int i = N_CLASSES - 1; i >= 1; --i) {
      uint32_t j = interval_draw(st, (uint32_t)i);
      int tmp = arr[i]; arr[i] = arr[j]; arr[j] = tmp;
    }
    for (int e = 0; e < 3; ++e) c.prime[node][e] = (int16_t)arr[e];
    for (int e = 0; e < 3; ++e) c.sub[node][e] = (int16_t)interval_draw(st, (uint32_t)(avail - 1));
  }
  return c;
}

constexpr Circuit CIRC = make_circuit();

// ---------------------------------------------------------------------------
// helpers
// ---------------------------------------------------------------------------
__device__ __forceinline__ uint16_t f2bf(float f) {
  uint32_t u = __builtin_bit_cast(uint32_t, f);
  uint32_t r = (u + 0x7fffu + ((u >> 16) & 1u)) >> 16;  // RNE
  return (uint16_t)r;
}
__device__ __forceinline__ float bf2f(uint16_t h) {
  uint32_t u = ((uint32_t)h) << 16;
  return __builtin_bit_cast(float, u);
}

__device__ __forceinline__ void load_lds16(const void* g, void* l) {
  __builtin_amdgcn_global_load_lds(
      (const __attribute__((address_space(1))) unsigned int*)g,
      (__attribute__((address_space(3))) unsigned int*)l, 16, 0, 0);
}

using bf16x8 = __attribute__((ext_vector_type(8))) short;
using f32x4  = __attribute__((ext_vector_type(4))) float;
using u16x8  = __attribute__((ext_vector_type(8))) unsigned short;
using u16x4  = __attribute__((ext_vector_type(4))) unsigned short;

// ds_read_b128 with compile-time offset immediate (no per-read VALU addr math)
template <int IMM>
__device__ __forceinline__ void dsr_i(bf16x8& d, uint32_t a) {
  asm volatile("ds_read_b128 %0, %1 offset:%2" : "=v"(d) : "v"(a), "n"(IMM));
}

// ---------------------------------------------------------------------------
// Circuit evaluation: fully unrolled, static indices only
// ---------------------------------------------------------------------------
template <int I>
__device__ __forceinline__ void eval_node(float (&vals)[N_VALS]) {
  if constexpr (I < N_INTERNAL) {
    constexpr int p0 = CIRC.prime[I][0], s0 = CIRC.sub[I][0];
    constexpr int p1 = CIRC.prime[I][1], s1 = CIRC.sub[I][1];
    constexpr int p2 = CIRC.prime[I][2], s2 = CIRC.sub[I][2];
    vals[2 * N_CLASSES + I] =
        vals[p0] * vals[s0] + vals[p1] * vals[s1] + vals[p2] * vals[s2];
    eval_node<I + 1>(vals);
  }
}

__global__ __launch_bounds__(256) void circuit_kernel(
    const float* __restrict__ probs, float* __restrict__ out, int B) {
  int r = blockIdx.x * blockDim.x + threadIdx.x;
  if (r >= B) return;
  float vals[N_VALS];
#pragma unroll
  for (int c = 0; c < N_CLASSES; ++c) {
    float p = probs[r * N_CLASSES + c];
    vals[c] = p;
    vals[N_CLASSES + c] = 1.0f - p;
  }
  eval_node<0>(vals);
  out[r] = vals[N_VALS - 1];
}

// ---------------------------------------------------------------------------
// x [B,784] f32 -> xb [B,896] bf16, one row per block, float4 loads (G13)
// ---------------------------------------------------------------------------
__global__ __launch_bounds__(256) void convert_pad_x(
    const float* __restrict__ x, uint16_t* __restrict__ xb) {
  const int r = blockIdx.x;
  const int t = threadIdx.x;
  if (t < D_IN / 4) {  // 196 threads convert
    float4 v = *reinterpret_cast<const float4*>(x + (size_t)r * D_IN + t * 4);
    u16x4 o;
    o[0] = f2bf(v.x); o[1] = f2bf(v.y); o[2] = f2bf(v.z); o[3] = f2bf(v.w);
    *reinterpret_cast<u16x4*>(xb + (size_t)r * KP1 + t * 4) = o;
  } else if (t < KP1 / 4) {  // threads 196..223 zero the pad
    u16x4 z = {0, 0, 0, 0};
    *reinterpret_cast<u16x4*>(xb + (size_t)r * KP1 + t * 4) = z;
  }
}

// ---------------------------------------------------------------------------
// W [K,N] f32 -> Wt [N,Kp] bf16 (transpose + convert, zero-pad k in [K,Kp))
// 64x64 tile, float4 global loads, ushort8 (16B) global stores.
// LDS bounce float[64][65]; both phases verified <=2-way bank aliasing (free).
// Requires N%64==0, Kp%64==0.
// ---------------------------------------------------------------------------
__global__ __launch_bounds__(256) void transpose_convert(
    const float* __restrict__ W, uint16_t* __restrict__ Wt,
    int K, int N, int Kp) {
  __shared__ float tile[64][65];
  const int kt = blockIdx.y * 64;
  const int nt = blockIdx.x * 64;
  const int t  = threadIdx.x;

  // load: 4 passes; thread -> row (t>>4)+16p, cols (t&15)*4..+3 (float4)
  const int lr = t >> 4;         // 0..15
  const int lc = (t & 15) * 4;   // 0..60
#pragma unroll
  for (int p = 0; p < 4; ++p) {
    const int row = lr + p * 16;
    const int k = kt + row;
    float4 v = {0.f, 0.f, 0.f, 0.f};
    if (k < K) v = *reinterpret_cast<const float4*>(W + (size_t)k * N + nt + lc);
    tile[row][lc + 0] = v.x;
    tile[row][lc + 1] = v.y;
    tile[row][lc + 2] = v.z;
    tile[row][lc + 3] = v.w;
  }
  __syncthreads();

  // write: 2 passes; thread -> n = nt+(t>>3)+32p, k-chunk (t&7)*8 (ushort8)
  const int wn = t >> 3;        // 0..31
  const int k8 = (t & 7) * 8;   // 0..56
#pragma unroll
  for (int p = 0; p < 2; ++p) {
    const int n = nt + wn + 32 * p;
    u16x8 o;
#pragma unroll
    for (int i = 0; i < 8; ++i) o[i] = f2bf(tile[k8 + i][wn + 32 * p]);
    *reinterpret_cast<u16x8*>(Wt + (size_t)n * Kp + kt + k8) = o;
  }
}

// ---------------------------------------------------------------------------
// 256x256 8-phase bf16 MFMA GEMM (m201-style template, single-barrier phases):
//   C[M,N] = relu(A[M,K] @ Bt[N,K]^T + bias[N]), bf16 in/out, f32 accum.
// 512 threads = 8 waves (2Mx4N), per-wave 128x64 output. BK=64, 2 K-tiles/iter,
// 8 phases/iter, quadrant order (00),(01),(11),(10); B0 re-read in phase 4.
// ONE barrier per phase (post-MFMA); WAR/RAW safety per R9 analysis.
// VGPR budget: ds_read addrs = 4 VGPRs + offset immediates; staging offsets =
// 2 VGPRs (uniform row deltas folded into SGPR pointer). Demand ~122 < 128.
// LDS 128 KiB, row-permuted halves + slot^=(row&7) XOR swizzle; staging =
// linear LDS dest + inverse-swizzled per-lane source. Counted vmcnt(6) at
// phases 4/8 only. Requires: M%256==0, N%256==0, K%128==0, K>=256.
// R9 measured: 221.5us @ L2 (1240 TF), MfmaUtil 57%, conflicts 0, no spill.
// ---------------------------------------------------------------------------
template <int MH, int NH, int BUF, bool RA, bool RB, int VM, typename F>
__device__ __forceinline__ void phase_t(
    uint32_t aA0, uint32_t aA1, uint32_t bA0, uint32_t bA1,
    bf16x8 (&Ar)[4][2], bf16x8 (&Br)[2][2][2], f32x4 (&acc)[2][2][4][2],
    F&& stage) {
  constexpr int AO = BUF * 32768 + MH * 16384;
  constexpr int BO = BUF * 32768 + NH * 16384;
  // 1. ds_read fragments (volatile asm — pinned within the phase's barriers)
  if constexpr (RA) {
    dsr_i<AO + 0 * 2048>(Ar[0][0], aA0); dsr_i<AO + 0 * 2048>(Ar[0][1], aA1);
    dsr_i<AO + 1 * 2048>(Ar[1][0], aA0); dsr_i<AO + 1 * 2048>(Ar[1][1], aA1);
    dsr_i<AO + 2 * 2048>(Ar[2][0], aA0); dsr_i<AO + 2 * 2048>(Ar[2][1], aA1);
    dsr_i<AO + 3 * 2048>(Ar[3][0], aA0); dsr_i<AO + 3 * 2048>(Ar[3][1], aA1);
  }
  if constexpr (RB) {
    dsr_i<BO + 0 * 2048>(Br[NH][0][0], bA0); dsr_i<BO + 0 * 2048>(Br[NH][0][1], bA1);
    dsr_i<BO + 1 * 2048>(Br[NH][1][0], bA0); dsr_i<BO + 1 * 2048>(Br[NH][1][1], bA1);
  }
  // 2. stage issues (global_load_lds) for this phase
  stage();
  // 3. wait own LDS reads; MFMA cluster (no pre-MFMA barrier)
  asm volatile("s_waitcnt lgkmcnt(0)" ::: "memory");
  __builtin_amdgcn_sched_barrier(0);  // rule #18: pin MFMAs below the wait
  __builtin_amdgcn_s_setprio(1);
#pragma unroll
  for (int m = 0; m < 4; ++m)
#pragma unroll
    for (int nf = 0; nf < 2; ++nf) {
      acc[MH][NH][m][nf] = __builtin_amdgcn_mfma_f32_16x16x32_bf16(
          Ar[m][0], Br[NH][nf][0], acc[MH][NH][m][nf], 0, 0, 0);
      acc[MH][NH][m][nf] = __builtin_amdgcn_mfma_f32_16x16x32_bf16(
          Ar[m][1], Br[NH][nf][1], acc[MH][NH][m][nf], 0, 0, 0);
    }
  __builtin_amdgcn_s_setprio(0);
  // 4. counted vmcnt (confirms the tile read after the NEXT barrier)
  if constexpr (VM >= 0) asm volatile("s_waitcnt vmcnt(%0)" :: "i"(VM) : "memory");
  __builtin_amdgcn_s_barrier();
}

__global__ __launch_bounds__(512, 1) void gemm256_bf16(
    const uint16_t* __restrict__ A, const uint16_t* __restrict__ Bt,
    const float* __restrict__ bias, uint16_t* __restrict__ C,
    int M, int N, int K) {
  extern __shared__ char smem[];

  const int t    = threadIdx.x;
  const int t16  = t * 16;
  const int lane = t & 63;
  const int wid  = t >> 6;
  const int wr   = wid >> 2;   // 0..1
  const int wc   = wid & 3;    // 0..3
  const int fr   = lane & 15;
  const int fq   = lane >> 4;

  // XCD-aware bijective swizzle (nwg % 8 == 0 for both layers)
  const int gx = gridDim.x, gy = gridDim.y;
  const int nwg = gx * gy;
  const int id  = blockIdx.y * gx + blockIdx.x;
  const int cpx = nwg >> 3;
  const int sid = (id & 7) * cpx + (id >> 3);
  const int row0 = (sid / gx) * 256;
  const int col0 = (sid % gx) * 256;

  const uint32_t Kb = (uint32_t)K * 2;

  // uniform (SGPR) staging base pointers: fold row0/col0
  const char* gA = (const char*)A + (size_t)row0 * Kb;
  const char* gB = (const char*)Bt + (size_t)col0 * Kb;

  // per-lane staging source offsets (2 VGPRs): row = t>>3, slot sg
  const uint32_t prow = (uint32_t)(t >> 3);
  const uint32_t sg   = (uint32_t)(((t & 7) ^ (t >> 3)) & 7) * 16u;
  const uint32_t srcA = prow * Kb + sg;
  const uint32_t srcB = (prow + 32u * (prow >> 5)) * Kb + sg;

  // uniform row deltas for the (h,j) staging variants
#define ROWA(h, j) ((h) * 64 + (j) * 128)
#define ROWB(h, j) ((h) * 32 + (j) * 128)

#define STAGE_A(v, h, kt) do { \
    load_lds16(gA + (size_t)(kt) * 128 + (size_t)ROWA(h, 0) * Kb + srcA, \
               smem + (v) * 32768 + (h) * 16384 + t16); \
    load_lds16(gA + (size_t)(kt) * 128 + (size_t)ROWA(h, 1) * Kb + srcA, \
               smem + (v) * 32768 + (h) * 16384 + 8192 + t16); } while (0)
#define STAGE_B(v, h, kt) do { \
    load_lds16(gB + (size_t)(kt) * 128 + (size_t)ROWB(h, 0) * Kb + srcB, \
               smem + 65536 + (v) * 32768 + (h) * 16384 + t16); \
    load_lds16(gB + (size_t)(kt) * 128 + (size_t)ROWB(h, 1) * Kb + srcB, \
               smem + 65536 + (v) * 32768 + (h) * 16384 + 8192 + t16); } while (0)

  // ---- per-thread ds_read base addresses (4 VGPRs; swizzle slot folded in)
  const uint32_t smb = (uint32_t)(size_t)(__attribute__((address_space(3))) char*)smem;
  const uint32_t s0v = (uint32_t)(((fq) ^ (fr & 7)) * 16);
  const uint32_t aA0 = smb + (uint32_t)((wr * 64 + fr) * 128) + s0v;
  const uint32_t aA1 = smb + (uint32_t)((wr * 64 + fr) * 128) + (s0v ^ 64u);
  const uint32_t bA0 = smb + 65536u + (uint32_t)((wc * 32 + fr) * 128) + s0v;
  const uint32_t bA1 = smb + 65536u + (uint32_t)((wc * 32 + fr) * 128) + (s0v ^ 64u);

  f32x4 acc[2][2][4][2];
#pragma unroll
  for (int a = 0; a < 2; ++a)
#pragma unroll
    for (int b = 0; b < 2; ++b)
#pragma unroll
      for (int m = 0; m < 4; ++m)
#pragma unroll
        for (int n = 0; n < 2; ++n) {
          acc[a][b][m][n][0] = 0.f; acc[a][b][m][n][1] = 0.f;
          acc[a][b][m][n][2] = 0.f; acc[a][b][m][n][3] = 0.f;
        }

  bf16x8 Ar[4][2], Br[2][2][2];

  // ---- prologue: tile0 fully (8 loads); tile1 minus B0 (6 loads)
  STAGE_A(0, 0, 0); STAGE_B(0, 0, 0); STAGE_A(0, 1, 0); STAGE_B(0, 1, 0);
  STAGE_A(1, 0, 1); STAGE_B(1, 1, 1); STAGE_A(1, 1, 1);
  asm volatile("s_waitcnt vmcnt(6)" ::: "memory");
  __builtin_amdgcn_s_barrier();

#define PH(MH_, NH_, RA_, RB_, VM_, BUF_, ...) \
  phase_t<MH_, NH_, BUF_, RA_, RB_, VM_>(aA0, aA1, bA0, bA1, \
                                         Ar, Br, acc, [&]() { __VA_ARGS__ })

  const int NI = K >> 7;  // iterations; 2 K-tiles each
  int i = 0;
  for (; i < NI - 1; ++i) {
    const int ktb = 2 * i + 1, ktc = 2 * i + 2, ktd = 2 * i + 3;
    PH(0, 0, true,  true,  -1, 0, STAGE_B(1, 0, ktb); );
    PH(0, 1, false, true,  -1, 0, STAGE_A(0, 0, ktc); );
    PH(1, 1, true,  false, -1, 0, STAGE_B(0, 1, ktc); );
    PH(1, 0, false, true,   6, 0, STAGE_A(0, 1, ktc); );
    PH(0, 0, true,  true,  -1, 1, STAGE_B(0, 0, ktc); );
    PH(0, 1, false, true,  -1, 1, STAGE_A(1, 0, ktd); );
    PH(1, 1, true,  false, -1, 1, STAGE_B(1, 1, ktd); );
    PH(1, 0, false, true,   6, 1, STAGE_A(1, 1, ktd); );
  }
  // peeled last iteration: stage only tile b's deferred B0, then drain
  {
    const int ktb = 2 * i + 1;
    PH(0, 0, true,  true,  -1, 0, STAGE_B(1, 0, ktb); );
    PH(0, 1, false, true,  -1, 0, );
    PH(1, 1, true,  false, -1, 0, );
    PH(1, 0, false, true,   0, 0, );
    PH(0, 0, true,  true,  -1, 1, );
    PH(0, 1, false, true,  -1, 1, );
    PH(1, 1, true,  false, -1, 1, );
    PH(1, 0, false, true,  -1, 1, );
  }
#undef PH
#undef STAGE_A
#undef STAGE_B
#undef ROWA
#undef ROWB

  // ---- epilogue: bias + relu + bf16 store
  // C/D layout: col = lane&15, row = (lane>>4)*4 + j   [measured m89]
#pragma unroll
  for (int mh = 0; mh < 2; ++mh)
#pragma unroll
    for (int nh = 0; nh < 2; ++nh)
#pragma unroll
      for (int m = 0; m < 4; ++m)
#pragma unroll
        for (int nf = 0; nf < 2; ++nf) {
          const int row = row0 + wr * 128 + mh * 64 + m * 16 + fq * 4;
          const int col = col0 + wc * 64 + nh * 32 + nf * 16 + fr;
          const float bv = bias[col];
          const size_t base = (size_t)row * N + col;
#pragma unroll
          for (int j = 0; j < 4; ++j) {
            float v = acc[mh][nh][m][nf][j] + bv;
            v = fmaxf(v, 0.0f);
            C[base + (size_t)j * N] = f2bf(v);
          }
        }
}

// ---------------------------------------------------------------------------
// logits (K=4096, N=10) + softmax -> probs[B,10]; one wave per row; h2 bf16
// ---------------------------------------------------------------------------
__global__ __launch_bounds__(256) void logits_softmax_kernel(
    const uint16_t* __restrict__ h2, const float* __restrict__ W3,
    const float* __restrict__ b3, float* __restrict__ probs, int B) {
  const int wave = threadIdx.x >> 6;
  const int lane = threadIdx.x & 63;
  const int row  = blockIdx.x * 4 + wave;
  if (row >= B) return;

  const uint16_t* hrow = h2 + (size_t)row * H_DIM;
  float acc[N_CLASSES];
#pragma unroll
  for (int c = 0; c < N_CLASSES; ++c) acc[c] = 0.0f;

#pragma unroll
  for (int it = 0; it < H_DIM / (64 * 8); ++it) {
    const int k0 = (it * 64 + lane) * 8;
    ushort4 u0 = *reinterpret_cast<const ushort4*>(hrow + k0);
    ushort4 u1 = *reinterpret_cast<const ushort4*>(hrow + k0 + 4);
    float hv[8] = {bf2f(u0.x), bf2f(u0.y), bf2f(u0.z), bf2f(u0.w),
                   bf2f(u1.x), bf2f(u1.y), bf2f(u1.z), bf2f(u1.w)};
#pragma unroll
    for (int q = 0; q < 8; ++q) {
      const float* wrow = W3 + (size_t)(k0 + q) * N_CLASSES;
#pragma unroll
      for (int c = 0; c < N_CLASSES; ++c) acc[c] = fmaf(hv[q], wrow[c], acc[c]);
    }
  }

#pragma unroll
  for (int c = 0; c < N_CLASSES; ++c) {
#pragma unroll
    for (int s = 32; s >= 1; s >>= 1) acc[c] += __shfl_xor(acc[c], s, 64);
  }

  if (lane == 0) {
    float l[N_CLASSES], m = -3.0e38f;
#pragma unroll
    for (int c = 0; c < N_CLASSES; ++c) {
      l[c] = acc[c] + b3[c];
      m = fmaxf(m, l[c]);
    }
    float sum = 0.0f;
#pragma unroll
    for (int c = 0; c < N_CLASSES; ++c) {
      l[c] = expf(l[c] - m);
      sum += l[c];
    }
    const float inv = 1.0f / sum;
#pragma unroll
    for (int c = 0; c < N_CLASSES; ++c) probs[row * N_CLASSES + c] = l[c] * inv;
  }
}

// ---------------------------------------------------------------------------
// launch.  ws layout (bf16 unless noted), total ~182 MB:
//   xb[8192*896] w1t[4096*896] w2t[4096*4096] h1[8192*4096] h2[8192*4096]
//   probs f32[8192*10]
// ---------------------------------------------------------------------------
extern "C" void kernel_launch(void* const* d_in, const int* in_sizes, int n_in,
                              void* d_out, int out_size, void* d_ws, size_t ws_size,
                              hipStream_t stream) {
  const float* x  = (const float*)d_in[0];
  const float* W1 = (const float*)d_in[1];
  const float* b1 = (const float*)d_in[2];
  const float* W2 = (const float*)d_in[3];
  const float* b2 = (const float*)d_in[4];
  const float* W3 = (const float*)d_in[5];
  const float* b3 = (const float*)d_in[6];
  float* out = (float*)d_out;

  uint16_t* xb  = (uint16_t*)d_ws;
  uint16_t* w1t = xb  + (size_t)B_SZ * KP1;
  uint16_t* w2t = w1t + (size_t)H_DIM * KP1;
  uint16_t* h1  = w2t + (size_t)H_DIM * H_DIM;
  uint16_t* h2  = h1  + (size_t)B_SZ * H_DIM;
  float* probs  = (float*)(h2 + (size_t)B_SZ * H_DIM);

  // allow 128 KiB dynamic LDS for the 8-phase GEMM (host-side attr, capture-safe)
  (void)hipFuncSetAttribute((const void*)gemm256_bf16,
                            hipFuncAttributeMaxDynamicSharedMemorySize, 131072);

  dim3 blk(256);

  // input conversions (vectorized: float4 loads, 16B bf16 stores)
  convert_pad_x<<<dim3(B_SZ), blk, 0, stream>>>(x, xb);
  transpose_convert<<<dim3(H_DIM / 64, KP1 / 64), blk, 0, stream>>>(W1, w1t, D_IN, H_DIM, KP1);
  transpose_convert<<<dim3(H_DIM / 64, H_DIM / 64), blk, 0, stream>>>(W2, w2t, H_DIM, H_DIM, H_DIM);

  // layer 1: h1 = relu(xb @ w1t^T + b1)   [8192,896]x[896,4096]
  gemm256_bf16<<<dim3(H_DIM / 256, B_SZ / 256), dim3(512), 131072, stream>>>(
      xb, w1t, b1, h1, B_SZ, H_DIM, KP1);

  // layer 2: h2 = relu(h1 @ w2t^T + b2)   [8192,4096]x[4096,4096]
  gemm256_bf16<<<dim3(H_DIM / 256, B_SZ / 256), dim3(512), 131072, stream>>>(
      h1, w2t, b2, h2, B_SZ, H_DIM, H_DIM);

  // layer 3 + softmax -> probs
  logits_softmax_kernel<<<dim3(B_SZ / 4), blk, 0, stream>>>(h2, W3, b3, probs, B_SZ);

  // circuit eval -> out[B]
  circuit_kernel<<<dim3(B_SZ / 256), blk, 0, stream>>>(probs, out, B_SZ);
}